// Round 9
// baseline (572.512 us; speedup 1.0000x reference)
//
#include <hip/hip_runtime.h>
#include <math.h>

// ---------------- problem constants ----------------
#define NB     8
#define NT     1000
#define NMEL   80
#define NFREQ  513      // 1024/2+1
#define NFFT   1024
#define WINL   1024
#define HOP    256
#define SIGL   256768   // (NT-1)*HOP + WINL
#define NFRM   8000     // NB*NT
#define NITER  8

// padded LDS indexing for FFT buffers
#define IDX(x) ((x) + ((x) >> 6))
#define LDS512 520      // IDX(511)=518 max

// ---------------- workspace layout (bytes) ----------------
#define OFF_G      ((size_t)0)                       // double G[80][80]
#define SZ_G       ((size_t)NMEL*NMEL*8)
#define OFF_GINV   (OFF_G + SZ_G)
#define SZ_GINV    ((size_t)NMEL*NMEL*8)
#define OFF_INVMEL (OFF_GINV + SZ_GINV)              // float invmelT[80][513]
#define SZ_INVMEL  ((size_t)NFREQ*NMEL*4)
#define OFF_WINF   (OFF_INVMEL + SZ_INVMEL)          // float winf[1024]
#define OFF_WINS   (OFF_WINF + 4096)                 // float wins[1024] (pre-scaled /512)
#define OFF_MAG    (OFF_WINS + 4096)                 // float mag[8000][513]
#define SZ_MAG     ((size_t)NFRM*NFREQ*4)
#define OFF_FR     (OFF_MAG + SZ_MAG)                // float frames[8000][1024]
#define SZ_FR      ((size_t)NFRM*NFFT*4)
#define OFF_SIG    (OFF_FR + SZ_FR)                  // float sig[8][256768]
#define SZ_SIG     ((size_t)NB*SIGL*4)

// ---------------- small precompute kernels ----------------

__global__ void k_windows(float* __restrict__ winf, float* __restrict__ wins) {
    int t = threadIdx.x; // 256 threads
    for (int n = t; n < WINL; n += 256) {
        double w = 0.5 - 0.5 * cos(2.0 * M_PI * (double)n / (double)WINL);
        winf[n] = (float)w;
    }
    __syncthreads();
    {
        float a0 = winf[t], a1 = winf[t + 256], a2 = winf[t + 512], a3 = winf[t + 768];
        float den = a0 * a0;
        den += a1 * a1; den += a2 * a2; den += a3 * a3;
        const float s = 1.0f / 512.0f;  // fold IFFT normalization into synthesis window
        wins[t]       = a0 / den * s;
        wins[t + 256] = a1 / den * s;
        wins[t + 512] = a2 / den * s;
        wins[t + 768] = a3 / den * s;
    }
}

// G = B B^T (f64)
__global__ void k_gram(const float* __restrict__ Bm, double* __restrict__ G) {
    int i = blockIdx.x; // 80 blocks
    for (int j = threadIdx.x; j < NMEL; j += blockDim.x) {
        double s = 0.0;
        for (int f = 0; f < NFREQ; ++f)
            s += (double)Bm[i * NFREQ + f] * (double)Bm[j * NFREQ + f];
        G[i * NMEL + j] = s;
    }
}

// Register-tiled GJ inversion of SPD 80x80 — ROLLED pivot loop (I$-resident),
// ONE barrier per pivot (publish raw pivot row + col simultaneously; each
// thread computes d locally; double-buffered LDS makes it race-free).
__global__ __launch_bounds__(256) void k_gjinv(const double* __restrict__ G,
                                               double* __restrict__ Ginv) {
    __shared__ double fcol[2][NMEL];
    __shared__ double prow[2][NMEL];   // RAW pivot row (unscaled)
    double A[5][5];
    const int t = threadIdx.x, tx = t & 15, ty = t >> 4;
    const int R0 = ty * 5, C0 = tx * 5;
#pragma unroll
    for (int r = 0; r < 5; ++r)
#pragma unroll
        for (int c = 0; c < 5; ++c)
            A[r][c] = G[(R0 + r) * NMEL + C0 + c];
    __syncthreads();
    for (int p = 0; p < NMEL; ++p) {
        const int pb = p / 5, pi = p - 5 * pb;   // runtime
        const int cur = p & 1;
        // publish pivot column (col owners) and RAW pivot row (row owners)
        if (tx == pb) {
#pragma unroll
            for (int r = 0; r < 5; ++r) {
                double v = A[r][0];
#pragma unroll
                for (int c = 1; c < 5; ++c) v = (c == pi) ? A[r][c] : v;
                fcol[cur][R0 + r] = v;
            }
        }
        if (ty == pb) {
#pragma unroll
            for (int c = 0; c < 5; ++c) {
                double v = A[0][c];
#pragma unroll
                for (int r = 1; r < 5; ++r) v = (r == pi) ? A[r][c] : v;
                prow[cur][C0 + c] = v;
            }
        }
        __syncthreads();
        const double d = 1.0 / fcol[cur][p];     // App
        double fr[5], pcd[5];
#pragma unroll
        for (int r = 0; r < 5; ++r) fr[r] = fcol[cur][R0 + r];
#pragma unroll
        for (int c = 0; c < 5; ++c) pcd[c] = prow[cur][C0 + c] * d;
#pragma unroll
        for (int r = 0; r < 5; ++r) {
            const bool pr = (ty == pb) && (r == pi);
#pragma unroll
            for (int c = 0; c < 5; ++c) {
                const bool pc = (tx == pb) && (c == pi);
                double nv;
                if (pr) nv = pc ? d : A[r][c] * d;
                else    nv = pc ? (-fr[r] * d) : fma(-fr[r], pcd[c], A[r][c]);
                A[r][c] = nv;
            }
        }
        // no trailing barrier: next pivot publishes into the other LDS buffer
    }
    __syncthreads();
#pragma unroll
    for (int r = 0; r < 5; ++r)
#pragma unroll
        for (int c = 0; c < 5; ++c)
            Ginv[(R0 + r) * NMEL + C0 + c] = A[r][c];
}

// invmelT[m][f] = sum_k B[k][f] * Ginv[k][m]   (TRANSPOSED output)
__global__ void k_invmel(const float* __restrict__ Bm, const double* __restrict__ Ginv,
                         float* __restrict__ ivT) {
    int idx = blockIdx.x * blockDim.x + threadIdx.x;
    if (idx >= NFREQ * NMEL) return;
    int f = idx / NMEL, m = idx - f * NMEL;
    double s = 0.0;
    for (int k = 0; k < NMEL; ++k)
        s += (double)Bm[k * NFREQ + f] * Ginv[k * NMEL + m];
    ivT[m * NFREQ + f] = (float)s;
}

// mag: fused melpow (10^(mel*scale+mean)) + 8 bt-rows per block GEMM-ish
#define MAGROWS 8
__global__ __launch_bounds__(256) void k_mag(const float* __restrict__ mel,
                                             const float* __restrict__ smean,
                                             const float* __restrict__ sscale,
                                             const float* __restrict__ ivT,
                                             float* __restrict__ mag) {
    __shared__ float rows[MAGROWS][NMEL];
    int bt0 = blockIdx.x * MAGROWS;
    for (int e = threadIdx.x; e < MAGROWS * NMEL; e += 256) {
        int m = e % NMEL;
        rows[e / NMEL][m] = exp10f(mel[(size_t)bt0 * NMEL + e] * sscale[m] + smean[m]);
    }
    __syncthreads();
    for (int f = threadIdx.x; f < NFREQ; f += 256) {
        float acc[MAGROWS];
#pragma unroll
        for (int r = 0; r < MAGROWS; ++r) acc[r] = 0.f;
        for (int m = 0; m < NMEL; ++m) {
            float iv = ivT[m * NFREQ + f];
#pragma unroll
            for (int r = 0; r < MAGROWS; ++r) acc[r] = fmaf(rows[r][m], iv, acc[r]);
        }
#pragma unroll
        for (int r = 0; r < MAGROWS; ++r)
            mag[(size_t)(bt0 + r) * NFREQ + f] = fmaxf(1e-10f, acc[r]);
    }
}

// ---------------- threefry2x32 (JAX-exact, partitionable mode) ----------------
__device__ inline unsigned rotl32(unsigned x, int d) { return (x << d) | (x >> (32 - d)); }

__device__ inline void threefry2x32(unsigned k0, unsigned k1, unsigned& x0, unsigned& x1) {
    unsigned ks0 = k0, ks1 = k1, ks2 = k0 ^ k1 ^ 0x1BD11BDAu;
    x0 += ks0; x1 += ks1;
#define TFR(r) { x0 += x1; x1 = rotl32(x1, r); x1 ^= x0; }
    TFR(13) TFR(15) TFR(26) TFR(6)   x0 += ks1; x1 += ks2 + 1u;
    TFR(17) TFR(29) TFR(16) TFR(24)  x0 += ks2; x1 += ks0 + 2u;
    TFR(13) TFR(15) TFR(26) TFR(6)   x0 += ks0; x1 += ks1 + 3u;
    TFR(17) TFR(29) TFR(16) TFR(24)  x0 += ks1; x1 += ks2 + 4u;
    TFR(13) TFR(15) TFR(26) TFR(6)   x0 += ks2; x1 += ks0 + 5u;
#undef TFR
}

__device__ inline float bits_to_unit(unsigned bits) {
    return __uint_as_float((bits >> 9) | 0x3F800000u) - 1.0f;
}

// precise libm trig here: runs once, feeds the whole pipeline
__device__ inline float2 rand_phase(int i) {
    unsigned x0 = 0u, x1 = (unsigned)i;
    threefry2x32(0u, 1u, x0, x1);
    float u = bits_to_unit(x0 ^ x1);
    float ang = 6.283185307179586f * u;
    return make_float2(cosf(ang), sinf(ang));
}

// ---------------- register twiddles via HW trig (input in REVOLUTIONS) --------
__device__ inline float2 cs_rev(float rev) {
    float r = rev - floorf(rev);
    return make_float2(__builtin_amdgcn_cosf(r), __builtin_amdgcn_sinf(r));
}

__device__ inline void make_twr(int w, float2 twr[4][3]) {
#pragma unroll
    for (int s = 0; s < 4; ++s) {
        const int msk = (1 << (2 * s)) - 1;
        const int base = w & ~msk;
#pragma unroll
        for (int kk = 1; kk <= 3; ++kk)
            twr[s][kk - 1] = cs_rev(-(float)(base * kk) * (1.0f / 512.0f));
    }
}

__device__ inline void make_ppr(int w, float2 ppr[4]) {
#pragma unroll
    for (int j = 0; j < 4; ++j)
        ppr[j] = cs_rev(-(float)(w + 128 * j) * (1.0f / 1024.0f));
}

// ---------------- 512-pt complex FFT (radix-4 x4 + radix-2), 128 lanes/frame ----
template <bool INV>
__device__ inline float2* fft512(float2* a, float2* b, const float2 twr[4][3],
                                 const int w) {
#pragma unroll
    for (int s = 0; s < 4; ++s) {
        const int slog = 2 * s;
        const int q = w & ((1 << slog) - 1);
        const int p = w >> slog;
        float2 x0 = a[IDX(w)];
        float2 x1 = a[IDX(w + 128)];
        float2 x2 = a[IDX(w + 256)];
        float2 x3 = a[IDX(w + 384)];
        float2 t0 = make_float2(x0.x + x2.x, x0.y + x2.y);
        float2 t1 = make_float2(x0.x - x2.x, x0.y - x2.y);
        float2 t2 = make_float2(x1.x + x3.x, x1.y + x3.y);
        float2 tm = make_float2(x1.x - x3.x, x1.y - x3.y);
        float2 it3 = INV ? make_float2(-tm.y, tm.x) : make_float2(tm.y, -tm.x);
        float2 y0 = make_float2(t0.x + t2.x, t0.y + t2.y);
        float2 u1 = make_float2(t1.x + it3.x, t1.y + it3.y);
        float2 u2 = make_float2(t0.x - t2.x, t0.y - t2.y);
        float2 u3 = make_float2(t1.x - it3.x, t1.y - it3.y);
        float2 w1 = twr[s][0], w2 = twr[s][1], w3 = twr[s][2];
        float s1 = INV ? -w1.y : w1.y;
        float s2 = INV ? -w2.y : w2.y;
        float s3 = INV ? -w3.y : w3.y;
        float2 y1 = make_float2(u1.x * w1.x - u1.y * s1, u1.x * s1 + u1.y * w1.x);
        float2 y2 = make_float2(u2.x * w2.x - u2.y * s2, u2.x * s2 + u2.y * w2.x);
        float2 y3 = make_float2(u3.x * w3.x - u3.y * s3, u3.x * s3 + u3.y * w3.x);
        const int wb = q + (p << (slog + 2));
        b[IDX(wb)]               = y0;
        b[IDX(wb + (1 << slog))] = y1;
        b[IDX(wb + (2 << slog))] = y2;
        b[IDX(wb + (3 << slog))] = y3;
        __syncthreads();
        float2* tsw = a; a = b; b = tsw;
    }
#pragma unroll
    for (int r = 0; r < 2; ++r) {
        const int bb = w + 128 * r;
        float2 x0 = a[IDX(bb)];
        float2 x1 = a[IDX(bb + 256)];
        b[IDX(bb)]       = make_float2(x0.x + x1.x, x0.y + x1.y);
        b[IDX(bb + 256)] = make_float2(x0.x - x1.x, x0.y - x1.y);
    }
    __syncthreads();
    return b;
}

// First ISTFT: X=mag*random_phase -> pack -> IFFT512 -> *syn -> frames
__global__ __launch_bounds__(256) void k_istft0(const float* __restrict__ mag,
                                                const float* __restrict__ wins,
                                                float* __restrict__ frames) {
    __shared__ float2 A[2][LDS512];
    __shared__ float2 B[2][LDS512];
    const int t = threadIdx.x, sub = t >> 7, w = t & 127;
    const int bt = blockIdx.x * 2 + sub;
    float2 twr[4][3], ppr[4];
    make_twr(w, twr);
    make_ppr(w, ppr);
    const float* mg = mag + (size_t)bt * NFREQ;
    auto loadX = [&](int k) -> float2 {
        float m = mg[k];
        float2 p = rand_phase(bt * NFREQ + k);
        float2 X = make_float2(m * p.x, m * p.y);
        if (k == 0 || k == 512) X.y = 0.f;
        return X;
    };
#pragma unroll
    for (int j = 0; j < 4; ++j) {
        int k = w + 128 * j;
        float2 Xk = loadX(k);
        float2 Xc = loadX(512 - k);
        float ex = 0.5f * (Xk.x + Xc.x), ey = 0.5f * (Xk.y - Xc.y);
        float dx = 0.5f * (Xk.x - Xc.x), dy = 0.5f * (Xk.y + Xc.y);
        float2 c = ppr[j];
        float ox = c.x * dx + c.y * dy;
        float oy = c.x * dy - c.y * dx;
        A[sub][IDX(k)] = make_float2(ex - oy, ey + ox);
    }
    __syncthreads();
    float2* res = fft512<true>(&A[sub][0], &B[sub][0], twr, w);
    float2* out2 = (float2*)(frames + (size_t)bt * NFFT);
    const float2* wn2 = (const float2*)wins;
#pragma unroll
    for (int j = 0; j < 4; ++j) {
        int n = w + 128 * j;
        float2 z = res[IDX(n)];
        float2 wv = wn2[n];
        out2[n] = make_float2(z.x * wv.x, z.y * wv.y);
    }
}

// FUSED Griffin-Lim step: STFT(sig) -> normalize -> *mag -> ISTFT -> frames.
// Per-lane Hermitian identity: with U = W^k*O[k], X[k] = E+U and
// X[512-k] = conj(E-U) -> no cross-lane exchange between the two FFTs.
__global__ __launch_bounds__(256) void k_fused(const float* __restrict__ sig,
                                               const float* __restrict__ mag,
                                               const float* __restrict__ winf,
                                               const float* __restrict__ wins,
                                               float* __restrict__ frames) {
    __shared__ float2 A[2][LDS512];
    __shared__ float2 B[2][LDS512];
    const int t = threadIdx.x, sub = t >> 7, w = t & 127;
    const int bt = blockIdx.x * 2 + sub;
    const int b = bt / NT, tt = bt - b * NT;
    const float2* x2 = (const float2*)(sig + (size_t)b * SIGL + (size_t)tt * HOP);
    const float2* wf2 = (const float2*)winf;
    const float* mg = mag + (size_t)bt * NFREQ;
    float2 twr[4][3], ppr[4];
    make_twr(w, twr);
    make_ppr(w, ppr);
    // forward: window + pack
#pragma unroll
    for (int j = 0; j < 4; ++j) {
        int n = w + 128 * j;
        float2 v = x2[n];
        float2 wv = wf2[n];
        A[sub][IDX(n)] = make_float2(v.x * wv.x, v.y * wv.y);
    }
    __syncthreads();
    float2* res = fft512<false>(&A[sub][0], &B[sub][0], twr, w);
    // unpack -> normalize -> *mag -> repack (all per-lane)
#pragma unroll
    for (int j = 0; j < 4; ++j) {
        int k = w + 128 * j;
        float2 Zk = res[IDX(k)];
        float2 C, D;   // C = X'[k], D = conj(X'[512-k])
        if (w == 0 && j == 0) {
            float X0 = Zk.x + Zk.y;    // X[0]
            float X5 = Zk.x - Zk.y;    // X[512]
            C = make_float2(X0 * (mg[0]   / fmaxf(1e-10f, fabsf(X0))), 0.f);
            D = make_float2(X5 * (mg[512] / fmaxf(1e-10f, fabsf(X5))), 0.f);
        } else {
            float2 Zc = res[IDX(512 - k)];
            float ex = 0.5f * (Zk.x + Zc.x), ey = 0.5f * (Zk.y - Zc.y);
            float dx = 0.5f * (Zk.x - Zc.x), dy = 0.5f * (Zk.y + Zc.y);
            float ox = dy, oy = -dx;               // O = -i*d
            float2 c = ppr[j];                      // W^k
            float Ux = c.x * ox - c.y * oy, Uy = c.x * oy + c.y * ox;
            float X1x = ex + Ux, X1y = ey + Uy;    // X[k]
            float X2x = ex - Ux, X2y = ey - Uy;    // conj(X[512-k])
            float i1 = mg[k]       / fmaxf(1e-10f, sqrtf(X1x * X1x + X1y * X1y));
            float i2 = mg[512 - k] / fmaxf(1e-10f, sqrtf(X2x * X2x + X2y * X2y));
            C = make_float2(X1x * i1, X1y * i1);
            D = make_float2(X2x * i2, X2y * i2);
        }
        // repack with Xk = C, Xc = conj(D)  (verbatim istft pack algebra)
        float ex = 0.5f * (C.x + D.x), ey = 0.5f * (C.y + D.y);
        float dx = 0.5f * (C.x - D.x), dy = 0.5f * (C.y - D.y);
        float2 c = ppr[j];
        float ox = c.x * dx + c.y * dy;
        float oy = c.x * dy - c.y * dx;
        A[sub][IDX(k)] = make_float2(ex - oy, ey + ox);
    }
    __syncthreads();
    float2* res2 = fft512<true>(&A[sub][0], &B[sub][0], twr, w);
    float2* out2 = (float2*)(frames + (size_t)bt * NFFT);
    const float2* wn2 = (const float2*)wins;
#pragma unroll
    for (int j = 0; j < 4; ++j) {
        int n = w + 128 * j;
        float2 z = res2[IDX(n)];
        float2 wv = wn2[n];
        out2[n] = make_float2(z.x * wv.x, z.y * wv.y);
    }
}

// overlap-add (gather): sig[b][l] = sum_t frames[b*NT+t][l-256t]
__global__ void k_ola(const float* __restrict__ frames, float* __restrict__ sig) {
    int idx = blockIdx.x * blockDim.x + threadIdx.x;
    if (idx >= NB * SIGL) return;
    int b = idx / SIGL, l = idx - b * SIGL;
    int tmax = min(NT - 1, l >> 8);
    int tmin = (l >= WINL) ? ((l - (WINL - HOP)) >> 8) : 0;
    float s = 0.f;
    for (int t = tmin; t <= tmax; ++t)
        s += frames[((size_t)(b * NT + t)) * NFFT + (l - (t << 8))];
    sig[idx] = s;
}

// ---------------- launcher ----------------
extern "C" void kernel_launch(void* const* d_in, const int* in_sizes, int n_in,
                              void* d_out, int out_size, void* d_ws, size_t ws_size,
                              hipStream_t stream) {
    const float* mel    = (const float*)d_in[0];
    const float* basis  = (const float*)d_in[1];
    const float* smean  = (const float*)d_in[2];
    const float* sscale = (const float*)d_in[3];

    char* ws = (char*)d_ws;
    double* G      = (double*)(ws + OFF_G);
    double* Ginv   = (double*)(ws + OFF_GINV);
    float*  ivT    = (float*) (ws + OFF_INVMEL);
    float*  winf   = (float*) (ws + OFF_WINF);
    float*  wins   = (float*) (ws + OFF_WINS);
    float*  mag    = (float*) (ws + OFF_MAG);
    float*  frames = (float*) (ws + OFF_FR);
    float*  sig    = (float*) (ws + OFF_SIG);
    float*  outp   = (float*)d_out;

    k_windows<<<1, 256, 0, stream>>>(winf, wins);
    k_gram<<<80, 256, 0, stream>>>(basis, G);
    k_gjinv<<<1, 256, 0, stream>>>(G, Ginv);
    k_invmel<<<(NFREQ * NMEL + 255) / 256, 256, 0, stream>>>(basis, Ginv, ivT);
    k_mag<<<NFRM / MAGROWS, 256, 0, stream>>>(mel, smean, sscale, ivT, mag);

    // iteration 0: random phase fused into first ISTFT
    k_istft0<<<NFRM / 2, 256, 0, stream>>>(mag, wins, frames);
    for (int it = 0; it < NITER; ++it) {
        k_ola<<<(NB * SIGL + 255) / 256, 256, 0, stream>>>(frames, sig);
        k_fused<<<NFRM / 2, 256, 0, stream>>>(sig, mag, winf, wins, frames);
    }
    k_ola<<<(NB * SIGL + 255) / 256, 256, 0, stream>>>(frames, outp);
}

// Round 10
// 517.505 us; speedup vs baseline: 1.1063x; 1.1063x over previous
//
#include <hip/hip_runtime.h>
#include <math.h>

// ---------------- problem constants ----------------
#define NB     8
#define NT     1000
#define NMEL   80
#define NFREQ  513      // 1024/2+1
#define NFFT   1024
#define WINL   1024
#define HOP    256
#define SIGL   256768   // (NT-1)*HOP + WINL
#define NFRM   8000     // NB*NT
#define NITER  8

// padded LDS indexing for FFT buffers
#define IDX(x) ((x) + ((x) >> 6))
#define LDS512 520      // IDX(511)=518 max

// packed 2xf32 — lowers to v_pk_add/mul/fma_f32 on CDNA
typedef float v2f __attribute__((ext_vector_type(2)));

// ---------------- workspace layout (bytes) ----------------
#define OFF_G      ((size_t)0)                       // double G[80][80]
#define SZ_G       ((size_t)NMEL*NMEL*8)
#define OFF_GINV   (OFF_G + SZ_G)
#define SZ_GINV    ((size_t)NMEL*NMEL*8)
#define OFF_INVMEL (OFF_GINV + SZ_GINV)              // float invmelT[80][513]
#define SZ_INVMEL  ((size_t)NFREQ*NMEL*4)
#define OFF_WINF   (OFF_INVMEL + SZ_INVMEL)          // float winf[1024]
#define OFF_WINS   (OFF_WINF + 4096)                 // float wins[1024] (pre-scaled /512)
#define OFF_MAG    (OFF_WINS + 4096)                 // float mag[8000][513]
#define SZ_MAG     ((size_t)NFRM*NFREQ*4)
#define OFF_FR     (OFF_MAG + SZ_MAG)                // float frames[8000][1024]
#define SZ_FR      ((size_t)NFRM*NFFT*4)
#define OFF_SIG    (OFF_FR + SZ_FR)                  // float sig[8][256768]
#define SZ_SIG     ((size_t)NB*SIGL*4)

// ---------------- small precompute kernels ----------------

__global__ void k_windows(float* __restrict__ winf, float* __restrict__ wins) {
    int t = threadIdx.x; // 256 threads
    for (int n = t; n < WINL; n += 256) {
        double w = 0.5 - 0.5 * cos(2.0 * M_PI * (double)n / (double)WINL);
        winf[n] = (float)w;
    }
    __syncthreads();
    {
        float a0 = winf[t], a1 = winf[t + 256], a2 = winf[t + 512], a3 = winf[t + 768];
        float den = a0 * a0;
        den += a1 * a1; den += a2 * a2; den += a3 * a3;
        const float s = 1.0f / 512.0f;  // fold IFFT normalization into synthesis window
        wins[t]       = a0 / den * s;
        wins[t + 256] = a1 / den * s;
        wins[t + 512] = a2 / den * s;
        wins[t + 768] = a3 / den * s;
    }
}

// G = B B^T (f64)
__global__ void k_gram(const float* __restrict__ Bm, double* __restrict__ G) {
    int i = blockIdx.x; // 80 blocks
    for (int j = threadIdx.x; j < NMEL; j += blockDim.x) {
        double s = 0.0;
        for (int f = 0; f < NFREQ; ++f)
            s += (double)Bm[i * NFREQ + f] * (double)Bm[j * NFREQ + f];
        G[i * NMEL + j] = s;
    }
}

// Register-tiled GJ inversion of SPD 80x80. Outer pb loop RUNTIME (I$-resident
// ~3KB body), inner pi UNROLLED (all A[][] indices compile-time -> no scratch).
// __launch_bounds__(256,1): single-block kernel, let the allocator take ~90 VGPRs.
// One barrier per pivot via double-buffered publish (proven race-free r7/r9).
__global__ __launch_bounds__(256, 1) void k_gjinv(const double* __restrict__ G,
                                                  double* __restrict__ Ginv) {
    __shared__ double fcol[2][NMEL];
    __shared__ double prow[2][NMEL];   // RAW pivot row (unscaled)
    double A[5][5];
    const int t = threadIdx.x, tx = t & 15, ty = t >> 4;
    const int R0 = ty * 5, C0 = tx * 5;
#pragma unroll
    for (int r = 0; r < 5; ++r)
#pragma unroll
        for (int c = 0; c < 5; ++c)
            A[r][c] = G[(R0 + r) * NMEL + C0 + c];
    __syncthreads();
    for (int pb = 0; pb < 16; ++pb) {          // runtime: small code
        const bool rown = (ty == pb), cown = (tx == pb);
#pragma unroll
        for (int pi = 0; pi < 5; ++pi) {       // unrolled: static reg indices
            const int p = pb * 5 + pi;
            const int cur = p & 1;
            if (cown) {
#pragma unroll
                for (int r = 0; r < 5; ++r) fcol[cur][R0 + r] = A[r][pi];
            }
            if (rown) {
#pragma unroll
                for (int c = 0; c < 5; ++c) prow[cur][C0 + c] = A[pi][c];
            }
            __syncthreads();
            const double d = 1.0 / fcol[cur][p];
            double fr[5], pcd[5];
#pragma unroll
            for (int r = 0; r < 5; ++r) fr[r] = fcol[cur][R0 + r];
#pragma unroll
            for (int c = 0; c < 5; ++c) pcd[c] = prow[cur][C0 + c] * d;
#pragma unroll
            for (int r = 0; r < 5; ++r) {
                const bool pr = (r == pi) && rown;   // r==pi static
#pragma unroll
                for (int c = 0; c < 5; ++c) {
                    const bool pc = (c == pi) && cown;
                    double nv;
                    if (pr) nv = pc ? d : A[r][c] * d;
                    else    nv = pc ? (-fr[r] * d) : fma(-fr[r], pcd[c], A[r][c]);
                    A[r][c] = nv;
                }
            }
            // no trailing barrier: next pivot publishes into the other buffer
        }
    }
    __syncthreads();
#pragma unroll
    for (int r = 0; r < 5; ++r)
#pragma unroll
        for (int c = 0; c < 5; ++c)
            Ginv[(R0 + r) * NMEL + C0 + c] = A[r][c];
}

// invmelT[m][f] = sum_k B[k][f] * Ginv[k][m]   (TRANSPOSED output)
__global__ void k_invmel(const float* __restrict__ Bm, const double* __restrict__ Ginv,
                         float* __restrict__ ivT) {
    int idx = blockIdx.x * blockDim.x + threadIdx.x;
    if (idx >= NFREQ * NMEL) return;
    int f = idx / NMEL, m = idx - f * NMEL;
    double s = 0.0;
    for (int k = 0; k < NMEL; ++k)
        s += (double)Bm[k * NFREQ + f] * Ginv[k * NMEL + m];
    ivT[m * NFREQ + f] = (float)s;
}

// mag: fused melpow (10^(mel*scale+mean)) + 8 bt-rows per block GEMM-ish
#define MAGROWS 8
__global__ __launch_bounds__(256) void k_mag(const float* __restrict__ mel,
                                             const float* __restrict__ smean,
                                             const float* __restrict__ sscale,
                                             const float* __restrict__ ivT,
                                             float* __restrict__ mag) {
    __shared__ float rows[MAGROWS][NMEL];
    int bt0 = blockIdx.x * MAGROWS;
    for (int e = threadIdx.x; e < MAGROWS * NMEL; e += 256) {
        int m = e % NMEL;
        rows[e / NMEL][m] = exp10f(mel[(size_t)bt0 * NMEL + e] * sscale[m] + smean[m]);
    }
    __syncthreads();
    for (int f = threadIdx.x; f < NFREQ; f += 256) {
        float acc[MAGROWS];
#pragma unroll
        for (int r = 0; r < MAGROWS; ++r) acc[r] = 0.f;
        for (int m = 0; m < NMEL; ++m) {
            float iv = ivT[m * NFREQ + f];
#pragma unroll
            for (int r = 0; r < MAGROWS; ++r) acc[r] = fmaf(rows[r][m], iv, acc[r]);
        }
#pragma unroll
        for (int r = 0; r < MAGROWS; ++r)
            mag[(size_t)(bt0 + r) * NFREQ + f] = fmaxf(1e-10f, acc[r]);
    }
}

// ---------------- threefry2x32 (JAX-exact, partitionable mode) ----------------
__device__ inline unsigned rotl32(unsigned x, int d) { return (x << d) | (x >> (32 - d)); }

__device__ inline void threefry2x32(unsigned k0, unsigned k1, unsigned& x0, unsigned& x1) {
    unsigned ks0 = k0, ks1 = k1, ks2 = k0 ^ k1 ^ 0x1BD11BDAu;
    x0 += ks0; x1 += ks1;
#define TFR(r) { x0 += x1; x1 = rotl32(x1, r); x1 ^= x0; }
    TFR(13) TFR(15) TFR(26) TFR(6)   x0 += ks1; x1 += ks2 + 1u;
    TFR(17) TFR(29) TFR(16) TFR(24)  x0 += ks2; x1 += ks0 + 2u;
    TFR(13) TFR(15) TFR(26) TFR(6)   x0 += ks0; x1 += ks1 + 3u;
    TFR(17) TFR(29) TFR(16) TFR(24)  x0 += ks1; x1 += ks2 + 4u;
    TFR(13) TFR(15) TFR(26) TFR(6)   x0 += ks2; x1 += ks0 + 5u;
#undef TFR
}

__device__ inline float bits_to_unit(unsigned bits) {
    return __uint_as_float((bits >> 9) | 0x3F800000u) - 1.0f;
}

// precise libm trig here: runs once, feeds the whole pipeline
__device__ inline v2f rand_phase(int i) {
    unsigned x0 = 0u, x1 = (unsigned)i;
    threefry2x32(0u, 1u, x0, x1);
    float u = bits_to_unit(x0 ^ x1);
    float ang = 6.283185307179586f * u;
    return (v2f){cosf(ang), sinf(ang)};
}

// ---------------- register twiddles via HW trig (input in REVOLUTIONS) --------
__device__ inline v2f cs_rev(float rev) {
    float r = rev - floorf(rev);
    return (v2f){__builtin_amdgcn_cosf(r), __builtin_amdgcn_sinf(r)};
}

__device__ inline void make_twr(int w, v2f twr[4][3]) {
#pragma unroll
    for (int s = 0; s < 4; ++s) {
        const int msk = (1 << (2 * s)) - 1;
        const int base = w & ~msk;
#pragma unroll
        for (int kk = 1; kk <= 3; ++kk)
            twr[s][kk - 1] = cs_rev(-(float)(base * kk) * (1.0f / 512.0f));
    }
}

__device__ inline void make_ppr(int w, v2f ppr[4]) {
#pragma unroll
    for (int j = 0; j < 4; ++j)
        ppr[j] = cs_rev(-(float)(w + 128 * j) * (1.0f / 1024.0f));
}

// complex multiply a*b (CONJ: a*conj(b)) — pk_mul + pk_fma with folded fneg
template <bool CONJ>
__device__ inline v2f cmulT(v2f a, v2f b) {
    v2f bb = CONJ ? (v2f){b.x, -b.y} : b;
    v2f ax = __builtin_shufflevector(a, a, 0, 0);
    v2f ay = __builtin_shufflevector(a, a, 1, 1);
    v2f br = __builtin_shufflevector(bb, bb, 1, 0);
    v2f s  = ay * br;                    // (a.y*b.y, a.y*b.x)
    v2f sn = (v2f){-s.x, s.y};
    return ax * bb + sn;                 // (a.x*b.x - a.y*b.y, a.x*b.y + a.y*b.x)
}

// ---------------- 512-pt complex FFT (radix-4 x4 + radix-2), 128 lanes/frame ----
template <bool INV>
__device__ inline v2f* fft512(v2f* a, v2f* b, const v2f twr[4][3], const int w) {
#pragma unroll
    for (int s = 0; s < 4; ++s) {
        const int slog = 2 * s;
        const int q = w & ((1 << slog) - 1);
        const int p = w >> slog;
        v2f x0 = a[IDX(w)];
        v2f x1 = a[IDX(w + 128)];
        v2f x2 = a[IDX(w + 256)];
        v2f x3 = a[IDX(w + 384)];
        v2f t0 = x0 + x2;
        v2f t1 = x0 - x2;
        v2f t2 = x1 + x3;
        v2f tm = x1 - x3;
        v2f it3 = INV ? (v2f){-tm.y, tm.x} : (v2f){tm.y, -tm.x};
        v2f y0 = t0 + t2;
        v2f u1 = t1 + it3;
        v2f u2 = t0 - t2;
        v2f u3 = t1 - it3;
        v2f y1 = cmulT<INV>(u1, twr[s][0]);
        v2f y2 = cmulT<INV>(u2, twr[s][1]);
        v2f y3 = cmulT<INV>(u3, twr[s][2]);
        const int wb = q + (p << (slog + 2));
        b[IDX(wb)]               = y0;
        b[IDX(wb + (1 << slog))] = y1;
        b[IDX(wb + (2 << slog))] = y2;
        b[IDX(wb + (3 << slog))] = y3;
        __syncthreads();
        v2f* tsw = a; a = b; b = tsw;
    }
#pragma unroll
    for (int r = 0; r < 2; ++r) {
        const int bb = w + 128 * r;
        v2f x0 = a[IDX(bb)];
        v2f x1 = a[IDX(bb + 256)];
        b[IDX(bb)]       = x0 + x1;
        b[IDX(bb + 256)] = x0 - x1;
    }
    __syncthreads();
    return b;
}

// First ISTFT: X=mag*random_phase -> pack -> IFFT512 -> *syn -> frames
__global__ __launch_bounds__(256) void k_istft0(const float* __restrict__ mag,
                                                const float* __restrict__ wins,
                                                float* __restrict__ frames) {
    __shared__ v2f A[2][LDS512];
    __shared__ v2f B[2][LDS512];
    const int t = threadIdx.x, sub = t >> 7, w = t & 127;
    const int bt = blockIdx.x * 2 + sub;
    v2f twr[4][3], ppr[4];
    make_twr(w, twr);
    make_ppr(w, ppr);
    const float* mg = mag + (size_t)bt * NFREQ;
    auto loadX = [&](int k) -> v2f {
        float m = mg[k];
        v2f p = rand_phase(bt * NFREQ + k);
        v2f X = (v2f){m * p.x, m * p.y};
        if (k == 0 || k == 512) X.y = 0.f;
        return X;
    };
#pragma unroll
    for (int j = 0; j < 4; ++j) {
        int k = w + 128 * j;
        v2f Xk = loadX(k);
        v2f Xc = loadX(512 - k);
        float ex = 0.5f * (Xk.x + Xc.x), ey = 0.5f * (Xk.y - Xc.y);
        float dx = 0.5f * (Xk.x - Xc.x), dy = 0.5f * (Xk.y + Xc.y);
        v2f c = ppr[j];
        float ox = c.x * dx + c.y * dy;
        float oy = c.x * dy - c.y * dx;
        A[sub][IDX(k)] = (v2f){ex - oy, ey + ox};
    }
    __syncthreads();
    v2f* res = fft512<true>(&A[sub][0], &B[sub][0], twr, w);
    v2f* out2 = (v2f*)(frames + (size_t)bt * NFFT);
    const v2f* wn2 = (const v2f*)wins;
#pragma unroll
    for (int j = 0; j < 4; ++j) {
        int n = w + 128 * j;
        out2[n] = res[IDX(n)] * wn2[n];
    }
}

// FUSED Griffin-Lim step: STFT(sig) -> normalize -> *mag -> ISTFT -> frames.
__global__ __launch_bounds__(256) void k_fused(const float* __restrict__ sig,
                                               const float* __restrict__ mag,
                                               const float* __restrict__ winf,
                                               const float* __restrict__ wins,
                                               float* __restrict__ frames) {
    __shared__ v2f A[2][LDS512];
    __shared__ v2f B[2][LDS512];
    const int t = threadIdx.x, sub = t >> 7, w = t & 127;
    const int bt = blockIdx.x * 2 + sub;
    const int b = bt / NT, tt = bt - b * NT;
    const v2f* x2 = (const v2f*)(sig + (size_t)b * SIGL + (size_t)tt * HOP);
    const v2f* wf2 = (const v2f*)winf;
    const float* mg = mag + (size_t)bt * NFREQ;
    v2f twr[4][3], ppr[4];
    make_twr(w, twr);
    make_ppr(w, ppr);
    // forward: window + pack
#pragma unroll
    for (int j = 0; j < 4; ++j) {
        int n = w + 128 * j;
        A[sub][IDX(n)] = x2[n] * wf2[n];
    }
    __syncthreads();
    v2f* res = fft512<false>(&A[sub][0], &B[sub][0], twr, w);
    // unpack -> normalize -> *mag -> repack (all per-lane)
#pragma unroll
    for (int j = 0; j < 4; ++j) {
        int k = w + 128 * j;
        v2f Zk = res[IDX(k)];
        v2f C, D;   // C = X'[k], D = conj(X'[512-k])
        if (w == 0 && j == 0) {
            float X0 = Zk.x + Zk.y;    // X[0]
            float X5 = Zk.x - Zk.y;    // X[512]
            C = (v2f){X0 * (mg[0]   / fmaxf(1e-10f, fabsf(X0))), 0.f};
            D = (v2f){X5 * (mg[512] / fmaxf(1e-10f, fabsf(X5))), 0.f};
        } else {
            v2f Zc = res[IDX(512 - k)];
            float ex = 0.5f * (Zk.x + Zc.x), ey = 0.5f * (Zk.y - Zc.y);
            float dx = 0.5f * (Zk.x - Zc.x), dy = 0.5f * (Zk.y + Zc.y);
            float ox = dy, oy = -dx;               // O = -i*d
            v2f c = ppr[j];                         // W^k
            float Ux = c.x * ox - c.y * oy, Uy = c.x * oy + c.y * ox;
            float X1x = ex + Ux, X1y = ey + Uy;    // X[k]
            float X2x = ex - Ux, X2y = ey - Uy;    // conj(X[512-k])
            float i1 = mg[k]       / fmaxf(1e-10f, sqrtf(X1x * X1x + X1y * X1y));
            float i2 = mg[512 - k] / fmaxf(1e-10f, sqrtf(X2x * X2x + X2y * X2y));
            C = (v2f){X1x * i1, X1y * i1};
            D = (v2f){X2x * i2, X2y * i2};
        }
        // repack with Xk = C, Xc = conj(D)  (verbatim istft pack algebra)
        float ex = 0.5f * (C.x + D.x), ey = 0.5f * (C.y + D.y);
        float dx = 0.5f * (C.x - D.x), dy = 0.5f * (C.y - D.y);
        v2f c = ppr[j];
        float ox = c.x * dx + c.y * dy;
        float oy = c.x * dy - c.y * dx;
        A[sub][IDX(k)] = (v2f){ex - oy, ey + ox};
    }
    __syncthreads();
    v2f* res2 = fft512<true>(&A[sub][0], &B[sub][0], twr, w);
    v2f* out2 = (v2f*)(frames + (size_t)bt * NFFT);
    const v2f* wn2 = (const v2f*)wins;
#pragma unroll
    for (int j = 0; j < 4; ++j) {
        int n = w + 128 * j;
        out2[n] = res2[IDX(n)] * wn2[n];
    }
}

// overlap-add (gather): sig[b][l] = sum_t frames[b*NT+t][l-256t]
__global__ void k_ola(const float* __restrict__ frames, float* __restrict__ sig) {
    int idx = blockIdx.x * blockDim.x + threadIdx.x;
    if (idx >= NB * SIGL) return;
    int b = idx / SIGL, l = idx - b * SIGL;
    int tmax = min(NT - 1, l >> 8);
    int tmin = (l >= WINL) ? ((l - (WINL - HOP)) >> 8) : 0;
    float s = 0.f;
    for (int t = tmin; t <= tmax; ++t)
        s += frames[((size_t)(b * NT + t)) * NFFT + (l - (t << 8))];
    sig[idx] = s;
}

// ---------------- launcher ----------------
extern "C" void kernel_launch(void* const* d_in, const int* in_sizes, int n_in,
                              void* d_out, int out_size, void* d_ws, size_t ws_size,
                              hipStream_t stream) {
    const float* mel    = (const float*)d_in[0];
    const float* basis  = (const float*)d_in[1];
    const float* smean  = (const float*)d_in[2];
    const float* sscale = (const float*)d_in[3];

    char* ws = (char*)d_ws;
    double* G      = (double*)(ws + OFF_G);
    double* Ginv   = (double*)(ws + OFF_GINV);
    float*  ivT    = (float*) (ws + OFF_INVMEL);
    float*  winf   = (float*) (ws + OFF_WINF);
    float*  wins   = (float*) (ws + OFF_WINS);
    float*  mag    = (float*) (ws + OFF_MAG);
    float*  frames = (float*) (ws + OFF_FR);
    float*  sig    = (float*) (ws + OFF_SIG);
    float*  outp   = (float*)d_out;

    k_windows<<<1, 256, 0, stream>>>(winf, wins);
    k_gram<<<80, 256, 0, stream>>>(basis, G);
    k_gjinv<<<1, 256, 0, stream>>>(G, Ginv);
    k_invmel<<<(NFREQ * NMEL + 255) / 256, 256, 0, stream>>>(basis, Ginv, ivT);
    k_mag<<<NFRM / MAGROWS, 256, 0, stream>>>(mel, smean, sscale, ivT, mag);

    // iteration 0: random phase fused into first ISTFT
    k_istft0<<<NFRM / 2, 256, 0, stream>>>(mag, wins, frames);
    for (int it = 0; it < NITER; ++it) {
        k_ola<<<(NB * SIGL + 255) / 256, 256, 0, stream>>>(frames, sig);
        k_fused<<<NFRM / 2, 256, 0, stream>>>(sig, mag, winf, wins, frames);
    }
    k_ola<<<(NB * SIGL + 255) / 256, 256, 0, stream>>>(frames, outp);
}

// Round 11
// 466.112 us; speedup vs baseline: 1.2283x; 1.1103x over previous
//
#include <hip/hip_runtime.h>
#include <math.h>

// ---------------- problem constants ----------------
#define NB     8
#define NT     1000
#define NMEL   80
#define NFREQ  513      // 1024/2+1
#define NFFT   1024
#define WINL   1024
#define HOP    256
#define SIGL   256768   // (NT-1)*HOP + WINL
#define NFRM   8000     // NB*NT
#define NITER  8

// padded LDS indexing: +1 float2 per 8 (breaks stride-8/64 bank patterns)
#define IDX8(x) ((x) + ((x) >> 3))
#define LDSF    576     // IDX8(511)=574 max, rounded

// packed 2xf32 — lowers to v_pk_add/mul/fma_f32 on CDNA
typedef float v2f __attribute__((ext_vector_type(2)));

// ---------------- workspace layout (bytes) ----------------
#define OFF_G      ((size_t)0)                       // double G[80][80]
#define SZ_G       ((size_t)NMEL*NMEL*8)
#define OFF_GINV   (OFF_G + SZ_G)
#define SZ_GINV    ((size_t)NMEL*NMEL*8)
#define OFF_INVMEL (OFF_GINV + SZ_GINV)              // float invmelT[80][513]
#define SZ_INVMEL  ((size_t)NFREQ*NMEL*4)
#define OFF_WINF   (OFF_INVMEL + SZ_INVMEL)          // float winf[1024]
#define OFF_WINS   (OFF_WINF + 4096)                 // float wins[1024] (pre-scaled /512)
#define OFF_MAG    (OFF_WINS + 4096)                 // float mag[8000][513]
#define SZ_MAG     ((size_t)NFRM*NFREQ*4)
#define OFF_FR     (OFF_MAG + SZ_MAG)                // float frames[8000][1024]
#define SZ_FR      ((size_t)NFRM*NFFT*4)
#define OFF_SIG    (OFF_FR + SZ_FR)                  // float sig[8][256768]
#define SZ_SIG     ((size_t)NB*SIGL*4)

// ---------------- small precompute kernels ----------------

__global__ void k_windows(float* __restrict__ winf, float* __restrict__ wins) {
    int t = threadIdx.x; // 256 threads
    for (int n = t; n < WINL; n += 256) {
        double w = 0.5 - 0.5 * cos(2.0 * M_PI * (double)n / (double)WINL);
        winf[n] = (float)w;
    }
    __syncthreads();
    {
        float a0 = winf[t], a1 = winf[t + 256], a2 = winf[t + 512], a3 = winf[t + 768];
        float den = a0 * a0;
        den += a1 * a1; den += a2 * a2; den += a3 * a3;
        const float s = 1.0f / 512.0f;  // fold IFFT normalization into synthesis window
        wins[t]       = a0 / den * s;
        wins[t + 256] = a1 / den * s;
        wins[t + 512] = a2 / den * s;
        wins[t + 768] = a3 / den * s;
    }
}

// G = B B^T (f64)
__global__ void k_gram(const float* __restrict__ Bm, double* __restrict__ G) {
    int i = blockIdx.x; // 80 blocks
    for (int j = threadIdx.x; j < NMEL; j += blockDim.x) {
        double s = 0.0;
        for (int f = 0; f < NFREQ; ++f)
            s += (double)Bm[i * NFREQ + f] * (double)Bm[j * NFREQ + f];
        G[i * NMEL + j] = s;
    }
}

// Register-tiled GJ inversion of SPD 80x80 (round-10 version: no spill, ~I$-resident)
__global__ __launch_bounds__(256, 1) void k_gjinv(const double* __restrict__ G,
                                                  double* __restrict__ Ginv) {
    __shared__ double fcol[2][NMEL];
    __shared__ double prow[2][NMEL];
    double A[5][5];
    const int t = threadIdx.x, tx = t & 15, ty = t >> 4;
    const int R0 = ty * 5, C0 = tx * 5;
#pragma unroll
    for (int r = 0; r < 5; ++r)
#pragma unroll
        for (int c = 0; c < 5; ++c)
            A[r][c] = G[(R0 + r) * NMEL + C0 + c];
    __syncthreads();
    for (int pb = 0; pb < 16; ++pb) {
        const bool rown = (ty == pb), cown = (tx == pb);
#pragma unroll
        for (int pi = 0; pi < 5; ++pi) {
            const int p = pb * 5 + pi;
            const int cur = p & 1;
            if (cown) {
#pragma unroll
                for (int r = 0; r < 5; ++r) fcol[cur][R0 + r] = A[r][pi];
            }
            if (rown) {
#pragma unroll
                for (int c = 0; c < 5; ++c) prow[cur][C0 + c] = A[pi][c];
            }
            __syncthreads();
            const double d = 1.0 / fcol[cur][p];
            double fr[5], pcd[5];
#pragma unroll
            for (int r = 0; r < 5; ++r) fr[r] = fcol[cur][R0 + r];
#pragma unroll
            for (int c = 0; c < 5; ++c) pcd[c] = prow[cur][C0 + c] * d;
#pragma unroll
            for (int r = 0; r < 5; ++r) {
                const bool pr = (r == pi) && rown;
#pragma unroll
                for (int c = 0; c < 5; ++c) {
                    const bool pc = (c == pi) && cown;
                    double nv;
                    if (pr) nv = pc ? d : A[r][c] * d;
                    else    nv = pc ? (-fr[r] * d) : fma(-fr[r], pcd[c], A[r][c]);
                    A[r][c] = nv;
                }
            }
        }
    }
    __syncthreads();
#pragma unroll
    for (int r = 0; r < 5; ++r)
#pragma unroll
        for (int c = 0; c < 5; ++c)
            Ginv[(R0 + r) * NMEL + C0 + c] = A[r][c];
}

// invmelT[m][f] = sum_k B[k][f] * Ginv[k][m]   (TRANSPOSED output)
__global__ void k_invmel(const float* __restrict__ Bm, const double* __restrict__ Ginv,
                         float* __restrict__ ivT) {
    int idx = blockIdx.x * blockDim.x + threadIdx.x;
    if (idx >= NFREQ * NMEL) return;
    int f = idx / NMEL, m = idx - f * NMEL;
    double s = 0.0;
    for (int k = 0; k < NMEL; ++k)
        s += (double)Bm[k * NFREQ + f] * Ginv[k * NMEL + m];
    ivT[m * NFREQ + f] = (float)s;
}

// mag: fused melpow (10^(mel*scale+mean)) + 8 bt-rows per block GEMM-ish
#define MAGROWS 8
__global__ __launch_bounds__(256) void k_mag(const float* __restrict__ mel,
                                             const float* __restrict__ smean,
                                             const float* __restrict__ sscale,
                                             const float* __restrict__ ivT,
                                             float* __restrict__ mag) {
    __shared__ float rows[MAGROWS][NMEL];
    int bt0 = blockIdx.x * MAGROWS;
    for (int e = threadIdx.x; e < MAGROWS * NMEL; e += 256) {
        int m = e % NMEL;
        rows[e / NMEL][m] = exp10f(mel[(size_t)bt0 * NMEL + e] * sscale[m] + smean[m]);
    }
    __syncthreads();
    for (int f = threadIdx.x; f < NFREQ; f += 256) {
        float acc[MAGROWS];
#pragma unroll
        for (int r = 0; r < MAGROWS; ++r) acc[r] = 0.f;
        for (int m = 0; m < NMEL; ++m) {
            float iv = ivT[m * NFREQ + f];
#pragma unroll
            for (int r = 0; r < MAGROWS; ++r) acc[r] = fmaf(rows[r][m], iv, acc[r]);
        }
#pragma unroll
        for (int r = 0; r < MAGROWS; ++r)
            mag[(size_t)(bt0 + r) * NFREQ + f] = fmaxf(1e-10f, acc[r]);
    }
}

// ---------------- threefry2x32 (JAX-exact, partitionable mode) ----------------
__device__ inline unsigned rotl32(unsigned x, int d) { return (x << d) | (x >> (32 - d)); }

__device__ inline void threefry2x32(unsigned k0, unsigned k1, unsigned& x0, unsigned& x1) {
    unsigned ks0 = k0, ks1 = k1, ks2 = k0 ^ k1 ^ 0x1BD11BDAu;
    x0 += ks0; x1 += ks1;
#define TFR(r) { x0 += x1; x1 = rotl32(x1, r); x1 ^= x0; }
    TFR(13) TFR(15) TFR(26) TFR(6)   x0 += ks1; x1 += ks2 + 1u;
    TFR(17) TFR(29) TFR(16) TFR(24)  x0 += ks2; x1 += ks0 + 2u;
    TFR(13) TFR(15) TFR(26) TFR(6)   x0 += ks0; x1 += ks1 + 3u;
    TFR(17) TFR(29) TFR(16) TFR(24)  x0 += ks1; x1 += ks2 + 4u;
    TFR(13) TFR(15) TFR(26) TFR(6)   x0 += ks2; x1 += ks0 + 5u;
#undef TFR
}

__device__ inline float bits_to_unit(unsigned bits) {
    return __uint_as_float((bits >> 9) | 0x3F800000u) - 1.0f;
}

__device__ inline v2f rand_phase(int i) {
    unsigned x0 = 0u, x1 = (unsigned)i;
    threefry2x32(0u, 1u, x0, x1);
    float u = bits_to_unit(x0 ^ x1);
    float ang = 6.283185307179586f * u;
    return (v2f){cosf(ang), sinf(ang)};
}

// ---------------- register twiddles via HW trig (input in REVOLUTIONS) --------
__device__ inline v2f cs_rev(float rev) {
    float r = rev - floorf(rev);
    return (v2f){__builtin_amdgcn_cosf(r), __builtin_amdgcn_sinf(r)};
}

// complex multiply a*b (CONJ: a*conj(b)) — pk_mul + pk_fma with folded fneg
template <bool CONJ>
__device__ inline v2f cmulT(v2f a, v2f b) {
    v2f bb = CONJ ? (v2f){b.x, -b.y} : b;
    v2f ax = __builtin_shufflevector(a, a, 0, 0);
    v2f ay = __builtin_shufflevector(a, a, 1, 1);
    v2f br = __builtin_shufflevector(bb, bb, 1, 0);
    v2f s  = ay * br;
    v2f sn = (v2f){-s.x, s.y};
    return ax * bb + sn;
}

// ---------------- in-register DFT8 (DIT 2x4) ----------------
template <bool INV>
__device__ inline void dft8(const v2f x[8], v2f y[8]) {
    v2f a0 = x[0] + x[4], a1 = x[0] - x[4];
    v2f a2 = x[2] + x[6], a3 = x[2] - x[6];
    v2f ja3 = INV ? (v2f){-a3.y, a3.x} : (v2f){a3.y, -a3.x};   // ∓i·a3
    v2f E0 = a0 + a2, E2 = a0 - a2;
    v2f E1 = a1 + ja3, E3 = a1 - ja3;
    v2f b0 = x[1] + x[5], b1 = x[1] - x[5];
    v2f b2 = x[3] + x[7], b3 = x[3] - x[7];
    v2f jb3 = INV ? (v2f){-b3.y, b3.x} : (v2f){b3.y, -b3.x};
    v2f O0 = b0 + b2, O2 = b0 - b2;
    v2f O1 = b1 + jb3, O3 = b1 - jb3;
    const float r = 0.70710678118654752f;
    v2f W1 = INV ? (v2f){r * (O1.x - O1.y), r * (O1.x + O1.y)}
                 : (v2f){r * (O1.x + O1.y), r * (O1.y - O1.x)};
    v2f W2 = INV ? (v2f){-O2.y, O2.x} : (v2f){O2.y, -O2.x};
    v2f W3 = INV ? (v2f){-r * (O3.x + O3.y), r * (O3.x - O3.y)}
                 : (v2f){r * (O3.y - O3.x), -r * (O3.x + O3.y)};
    y[0] = E0 + O0;  y[4] = E0 - O0;
    y[1] = E1 + W1;  y[5] = E1 - W1;
    y[2] = E2 + W2;  y[6] = E2 - W2;
    y[3] = E3 + W3;  y[7] = E3 - W3;
}

// ---------------- wave-synchronous 512-pt FFT, radix-8^3 ---------------------
// One wave64 per frame; lane lam holds elements n = lam + 64*j in z[j].
// Stage 1 pure-register; stages 2,3 via LDS (no barriers: wave-owned buffer,
// lockstep wave64 + in-order DS pipe => read-all-then-write-all is hazard-free).
// Twiddles (fwd, conj'd at use for INV): tw0[m-1]=W512^{lam*m}, tw1[m-1]=W64^{(lam>>3)*m}.
// Result returns in z[j] = element (lam + 64*j), natural order.
template <bool INV>
__device__ inline void fft512r8(v2f z[8], v2f* __restrict__ L,
                                const v2f tw0[7], const v2f tw1[7], const int lam) {
    v2f y[8], x[8];
    dft8<INV>(z, y);
#pragma unroll
    for (int m = 1; m < 8; ++m) y[m] = cmulT<INV>(y[m], tw0[m - 1]);
#pragma unroll
    for (int m = 0; m < 8; ++m) L[IDX8(8 * lam + m)] = y[m];
#pragma unroll
    for (int m = 0; m < 8; ++m) x[m] = L[IDX8(lam + 64 * m)];
    dft8<INV>(x, y);
#pragma unroll
    for (int m = 1; m < 8; ++m) y[m] = cmulT<INV>(y[m], tw1[m - 1]);
    const int q = lam & 7, p = lam >> 3;
#pragma unroll
    for (int m = 0; m < 8; ++m) L[IDX8(q + 64 * p + 8 * m)] = y[m];
#pragma unroll
    for (int m = 0; m < 8; ++m) x[m] = L[IDX8(lam + 64 * m)];
    dft8<INV>(x, z);
}

// First ISTFT: X=mag*random_phase -> pack (global pairs) -> IFFT512 -> *syn
__global__ __launch_bounds__(256) void k_istft0(const float* __restrict__ mag,
                                                const float* __restrict__ wins,
                                                float* __restrict__ frames) {
    __shared__ v2f L[4][LDSF];
    const int t = threadIdx.x, sub = t >> 6, lam = t & 63;
    const int bt = blockIdx.x * 4 + sub;
    v2f tw0[7], tw1[7], ppr[8];
#pragma unroll
    for (int m = 1; m < 8; ++m) {
        tw0[m - 1] = cs_rev(-(float)(lam * m) * (1.0f / 512.0f));
        tw1[m - 1] = cs_rev(-(float)((lam >> 3) * m) * (1.0f / 64.0f));
    }
#pragma unroll
    for (int j = 0; j < 8; ++j)
        ppr[j] = cs_rev(-(float)(lam + 64 * j) * (1.0f / 1024.0f));
    const float* mg = mag + (size_t)bt * NFREQ;
    auto loadX = [&](int k) -> v2f {
        float m = mg[k];
        v2f p = rand_phase(bt * NFREQ + k);
        v2f X = (v2f){m * p.x, m * p.y};
        if (k == 0 || k == 512) X.y = 0.f;   // C2R drops imag of DC/Nyquist
        return X;
    };
    v2f z[8];
#pragma unroll
    for (int j = 0; j < 8; ++j) {
        int k = lam + 64 * j;
        v2f Xk = loadX(k);
        v2f Xc = loadX(512 - k);
        float ex = 0.5f * (Xk.x + Xc.x), ey = 0.5f * (Xk.y - Xc.y);
        float dx = 0.5f * (Xk.x - Xc.x), dy = 0.5f * (Xk.y + Xc.y);
        v2f c = ppr[j];                       // e^{-i th}; W^{-k} = conj(c)
        float ox = c.x * dx + c.y * dy;
        float oy = c.x * dy - c.y * dx;
        z[j] = (v2f){ex - oy, ey + ox};       // Z = Xe + i Xo
    }
    fft512r8<true>(z, &L[sub][0], tw0, tw1, lam);
    v2f* out2 = (v2f*)(frames + (size_t)bt * NFFT);
    const v2f* wn2 = (const v2f*)wins;        // wins pre-scaled by 1/512
#pragma unroll
    for (int j = 0; j < 8; ++j) {
        int n = lam + 64 * j;
        out2[n] = z[j] * wn2[n];
    }
}

// FUSED Griffin-Lim step: STFT(sig) -> normalize -> *mag -> ISTFT -> frames.
// Hermitian partner Z[512-k] fetched via one wave-local LDS exchange.
__global__ __launch_bounds__(256) void k_fused(const float* __restrict__ sig,
                                               const float* __restrict__ mag,
                                               const float* __restrict__ winf,
                                               const float* __restrict__ wins,
                                               float* __restrict__ frames) {
    __shared__ v2f L[4][LDSF];
    const int t = threadIdx.x, sub = t >> 6, lam = t & 63;
    const int bt = blockIdx.x * 4 + sub;
    const int b = bt / NT, tt = bt - b * NT;
    const v2f* x2 = (const v2f*)(sig + (size_t)b * SIGL + (size_t)tt * HOP);
    const v2f* wf2 = (const v2f*)winf;
    const float* mg = mag + (size_t)bt * NFREQ;
    v2f tw0[7], tw1[7], ppr[8];
#pragma unroll
    for (int m = 1; m < 8; ++m) {
        tw0[m - 1] = cs_rev(-(float)(lam * m) * (1.0f / 512.0f));
        tw1[m - 1] = cs_rev(-(float)((lam >> 3) * m) * (1.0f / 64.0f));
    }
#pragma unroll
    for (int j = 0; j < 8; ++j)
        ppr[j] = cs_rev(-(float)(lam + 64 * j) * (1.0f / 1024.0f));
    // forward: window + pack (z[n] = x[2n]w + i x[2n+1]w)
    v2f z[8];
#pragma unroll
    for (int j = 0; j < 8; ++j) {
        int n = lam + 64 * j;
        z[j] = x2[n] * wf2[n];
    }
    fft512r8<false>(z, &L[sub][0], tw0, tw1, lam);
    // exchange: fetch Zc[j] = Z[512-k] (partner lane 64-lam, slot 7-j; lane0: slot (8-j)&7)
#pragma unroll
    for (int j = 0; j < 8; ++j) L[sub][IDX8(lam + 64 * j)] = z[j];
    v2f Zc[8];
    const int lp = (64 - lam) & 63;
#pragma unroll
    for (int j = 0; j < 8; ++j) {
        int jp = lam ? (7 - j) : ((8 - j) & 7);
        Zc[j] = L[sub][IDX8(lp + 64 * jp)];
    }
    // unpack -> normalize -> *mag -> repack (per-lane, verbatim algebra)
#pragma unroll
    for (int j = 0; j < 8; ++j) {
        int k = lam + 64 * j;
        v2f Zk = z[j];
        v2f C, D;   // C = X'[k], D = conj(X'[512-k])
        if (lam == 0 && j == 0) {
            float X0 = Zk.x + Zk.y;    // X[0]
            float X5 = Zk.x - Zk.y;    // X[512]
            C = (v2f){X0 * (mg[0]   / fmaxf(1e-10f, fabsf(X0))), 0.f};
            D = (v2f){X5 * (mg[512] / fmaxf(1e-10f, fabsf(X5))), 0.f};
        } else {
            v2f Zp = Zc[j];
            float ex = 0.5f * (Zk.x + Zp.x), ey = 0.5f * (Zk.y - Zp.y);
            float dx = 0.5f * (Zk.x - Zp.x), dy = 0.5f * (Zk.y + Zp.y);
            float ox = dy, oy = -dx;               // O = -i*d
            v2f c = ppr[j];                         // W^k
            float Ux = c.x * ox - c.y * oy, Uy = c.x * oy + c.y * ox;
            float X1x = ex + Ux, X1y = ey + Uy;    // X[k]
            float X2x = ex - Ux, X2y = ey - Uy;    // conj(X[512-k])
            float i1 = mg[k]       / fmaxf(1e-10f, sqrtf(X1x * X1x + X1y * X1y));
            float i2 = mg[512 - k] / fmaxf(1e-10f, sqrtf(X2x * X2x + X2y * X2y));
            C = (v2f){X1x * i1, X1y * i1};
            D = (v2f){X2x * i2, X2y * i2};
        }
        // repack with Xk = C, Xc = conj(D)
        float ex = 0.5f * (C.x + D.x), ey = 0.5f * (C.y + D.y);
        float dx = 0.5f * (C.x - D.x), dy = 0.5f * (C.y - D.y);
        v2f c = ppr[j];
        float ox = c.x * dx + c.y * dy;
        float oy = c.x * dy - c.y * dx;
        z[j] = (v2f){ex - oy, ey + ox};
    }
    fft512r8<true>(z, &L[sub][0], tw0, tw1, lam);
    v2f* out2 = (v2f*)(frames + (size_t)bt * NFFT);
    const v2f* wn2 = (const v2f*)wins;
#pragma unroll
    for (int j = 0; j < 8; ++j) {
        int n = lam + 64 * j;
        out2[n] = z[j] * wn2[n];
    }
}

// overlap-add (gather): sig[b][l] = sum_t frames[b*NT+t][l-256t]
__global__ void k_ola(const float* __restrict__ frames, float* __restrict__ sig) {
    int idx = blockIdx.x * blockDim.x + threadIdx.x;
    if (idx >= NB * SIGL) return;
    int b = idx / SIGL, l = idx - b * SIGL;
    int tmax = min(NT - 1, l >> 8);
    int tmin = (l >= WINL) ? ((l - (WINL - HOP)) >> 8) : 0;
    float s = 0.f;
    for (int t = tmin; t <= tmax; ++t)
        s += frames[((size_t)(b * NT + t)) * NFFT + (l - (t << 8))];
    sig[idx] = s;
}

// ---------------- launcher ----------------
extern "C" void kernel_launch(void* const* d_in, const int* in_sizes, int n_in,
                              void* d_out, int out_size, void* d_ws, size_t ws_size,
                              hipStream_t stream) {
    const float* mel    = (const float*)d_in[0];
    const float* basis  = (const float*)d_in[1];
    const float* smean  = (const float*)d_in[2];
    const float* sscale = (const float*)d_in[3];

    char* ws = (char*)d_ws;
    double* G      = (double*)(ws + OFF_G);
    double* Ginv   = (double*)(ws + OFF_GINV);
    float*  ivT    = (float*) (ws + OFF_INVMEL);
    float*  winf   = (float*) (ws + OFF_WINF);
    float*  wins   = (float*) (ws + OFF_WINS);
    float*  mag    = (float*) (ws + OFF_MAG);
    float*  frames = (float*) (ws + OFF_FR);
    float*  sig    = (float*) (ws + OFF_SIG);
    float*  outp   = (float*)d_out;

    k_windows<<<1, 256, 0, stream>>>(winf, wins);
    k_gram<<<80, 256, 0, stream>>>(basis, G);
    k_gjinv<<<1, 256, 0, stream>>>(G, Ginv);
    k_invmel<<<(NFREQ * NMEL + 255) / 256, 256, 0, stream>>>(basis, Ginv, ivT);
    k_mag<<<NFRM / MAGROWS, 256, 0, stream>>>(mel, smean, sscale, ivT, mag);

    // iteration 0: random phase fused into first ISTFT
    k_istft0<<<NFRM / 4, 256, 0, stream>>>(mag, wins, frames);
    for (int it = 0; it < NITER; ++it) {
        k_ola<<<(NB * SIGL + 255) / 256, 256, 0, stream>>>(frames, sig);
        k_fused<<<NFRM / 4, 256, 0, stream>>>(sig, mag, winf, wins, frames);
    }
    k_ola<<<(NB * SIGL + 255) / 256, 256, 0, stream>>>(frames, outp);
}

// Round 13
// 430.178 us; speedup vs baseline: 1.3309x; 1.0835x over previous
//
#include <hip/hip_runtime.h>
#include <math.h>

// ---------------- problem constants ----------------
#define NB     8
#define NT     1000
#define NMEL   80
#define NFREQ  513      // 1024/2+1
#define NFFT   1024
#define WINL   1024
#define HOP    256
#define SIGL   256768   // (NT-1)*HOP + WINL
#define NFRM   8000     // NB*NT
#define NITER  8

// padded LDS indexing: +1 float2 per 8 (breaks stride-8/64 bank patterns)
#define IDX8(x) ((x) + ((x) >> 3))
#define LDSF    584     // IDX8(512)=576 max (istft0 stores X[512]), rounded to 8

// packed 2xf32 — lowers to v_pk_add/mul/fma_f32 on CDNA
typedef float v2f __attribute__((ext_vector_type(2)));

// ---------------- workspace layout (bytes) ----------------
#define OFF_G      ((size_t)0)                       // double G[80][80]
#define SZ_G       ((size_t)NMEL*NMEL*8)
#define OFF_GINV   (OFF_G + SZ_G)
#define SZ_GINV    ((size_t)NMEL*NMEL*8)
#define OFF_INVMEL (OFF_GINV + SZ_GINV)              // float invmelT[80][513]
#define SZ_INVMEL  ((size_t)NFREQ*NMEL*4)
#define OFF_WINF   (OFF_INVMEL + SZ_INVMEL)          // float winf[1024]
#define OFF_WINS   (OFF_WINF + 4096)                 // float wins[1024] (pre-scaled /512)
#define OFF_MAG    (OFF_WINS + 4096)                 // float mag[8000][513]
#define SZ_MAG     ((size_t)NFRM*NFREQ*4)
#define OFF_FR     (OFF_MAG + SZ_MAG)                // float frames[8000][1024]
#define SZ_FR      ((size_t)NFRM*NFFT*4)
#define OFF_SIG    (OFF_FR + SZ_FR)                  // float sig[8][256768]
#define SZ_SIG     ((size_t)NB*SIGL*4)

// ---------------- small precompute kernels ----------------

__global__ void k_windows(float* __restrict__ winf, float* __restrict__ wins) {
    int t = threadIdx.x; // 256 threads
    for (int n = t; n < WINL; n += 256) {
        double w = 0.5 - 0.5 * cos(2.0 * M_PI * (double)n / (double)WINL);
        winf[n] = (float)w;
    }
    __syncthreads();
    {
        float a0 = winf[t], a1 = winf[t + 256], a2 = winf[t + 512], a3 = winf[t + 768];
        float den = a0 * a0;
        den += a1 * a1; den += a2 * a2; den += a3 * a3;
        const float s = 1.0f / 512.0f;  // fold IFFT normalization into synthesis window
        wins[t]       = a0 / den * s;
        wins[t + 256] = a1 / den * s;
        wins[t + 512] = a2 / den * s;
        wins[t + 768] = a3 / den * s;
    }
}

// G = B B^T (f64)
__global__ void k_gram(const float* __restrict__ Bm, double* __restrict__ G) {
    int i = blockIdx.x; // 80 blocks
    for (int j = threadIdx.x; j < NMEL; j += blockDim.x) {
        double s = 0.0;
        for (int f = 0; f < NFREQ; ++f)
            s += (double)Bm[i * NFREQ + f] * (double)Bm[j * NFREQ + f];
        G[i * NMEL + j] = s;
    }
}

// Register-tiled GJ inversion of SPD 80x80 (round-10 version: no spill, I$-resident)
__global__ __launch_bounds__(256, 1) void k_gjinv(const double* __restrict__ G,
                                                  double* __restrict__ Ginv) {
    __shared__ double fcol[2][NMEL];
    __shared__ double prow[2][NMEL];
    double A[5][5];
    const int t = threadIdx.x, tx = t & 15, ty = t >> 4;
    const int R0 = ty * 5, C0 = tx * 5;
#pragma unroll
    for (int r = 0; r < 5; ++r)
#pragma unroll
        for (int c = 0; c < 5; ++c)
            A[r][c] = G[(R0 + r) * NMEL + C0 + c];
    __syncthreads();
    for (int pb = 0; pb < 16; ++pb) {
        const bool rown = (ty == pb), cown = (tx == pb);
#pragma unroll
        for (int pi = 0; pi < 5; ++pi) {
            const int p = pb * 5 + pi;
            const int cur = p & 1;
            if (cown) {
#pragma unroll
                for (int r = 0; r < 5; ++r) fcol[cur][R0 + r] = A[r][pi];
            }
            if (rown) {
#pragma unroll
                for (int c = 0; c < 5; ++c) prow[cur][C0 + c] = A[pi][c];
            }
            __syncthreads();
            const double d = 1.0 / fcol[cur][p];
            double fr[5], pcd[5];
#pragma unroll
            for (int r = 0; r < 5; ++r) fr[r] = fcol[cur][R0 + r];
#pragma unroll
            for (int c = 0; c < 5; ++c) pcd[c] = prow[cur][C0 + c] * d;
#pragma unroll
            for (int r = 0; r < 5; ++r) {
                const bool pr = (r == pi) && rown;
#pragma unroll
                for (int c = 0; c < 5; ++c) {
                    const bool pc = (c == pi) && cown;
                    double nv;
                    if (pr) nv = pc ? d : A[r][c] * d;
                    else    nv = pc ? (-fr[r] * d) : fma(-fr[r], pcd[c], A[r][c]);
                    A[r][c] = nv;
                }
            }
        }
    }
    __syncthreads();
#pragma unroll
    for (int r = 0; r < 5; ++r)
#pragma unroll
        for (int c = 0; c < 5; ++c)
            Ginv[(R0 + r) * NMEL + C0 + c] = A[r][c];
}

// invmelT[m][f] = sum_k B[k][f] * Ginv[k][m]   (TRANSPOSED output)
__global__ void k_invmel(const float* __restrict__ Bm, const double* __restrict__ Ginv,
                         float* __restrict__ ivT) {
    int idx = blockIdx.x * blockDim.x + threadIdx.x;
    if (idx >= NFREQ * NMEL) return;
    int f = idx / NMEL, m = idx - f * NMEL;
    double s = 0.0;
    for (int k = 0; k < NMEL; ++k)
        s += (double)Bm[k * NFREQ + f] * Ginv[k * NMEL + m];
    ivT[m * NFREQ + f] = (float)s;
}

// mag: fused melpow (10^(mel*scale+mean)) + 16 bt-rows per block GEMM-ish
#define MAGROWS 16
__global__ __launch_bounds__(256) void k_mag(const float* __restrict__ mel,
                                             const float* __restrict__ smean,
                                             const float* __restrict__ sscale,
                                             const float* __restrict__ ivT,
                                             float* __restrict__ mag) {
    __shared__ float rows[MAGROWS][NMEL];
    int bt0 = blockIdx.x * MAGROWS;
    for (int e = threadIdx.x; e < MAGROWS * NMEL; e += 256) {
        int m = e % NMEL;
        rows[e / NMEL][m] = exp10f(mel[(size_t)bt0 * NMEL + e] * sscale[m] + smean[m]);
    }
    __syncthreads();
    for (int f = threadIdx.x; f < NFREQ; f += 256) {
        float acc[MAGROWS];
#pragma unroll
        for (int r = 0; r < MAGROWS; ++r) acc[r] = 0.f;
        for (int m = 0; m < NMEL; ++m) {
            float iv = ivT[m * NFREQ + f];
#pragma unroll
            for (int r = 0; r < MAGROWS; ++r) acc[r] = fmaf(rows[r][m], iv, acc[r]);
        }
#pragma unroll
        for (int r = 0; r < MAGROWS; ++r)
            mag[(size_t)(bt0 + r) * NFREQ + f] = fmaxf(1e-10f, acc[r]);
    }
}

// ---------------- threefry2x32 (JAX-exact, partitionable mode) ----------------
__device__ inline unsigned rotl32(unsigned x, int d) { return (x << d) | (x >> (32 - d)); }

__device__ inline void threefry2x32(unsigned k0, unsigned k1, unsigned& x0, unsigned& x1) {
    unsigned ks0 = k0, ks1 = k1, ks2 = k0 ^ k1 ^ 0x1BD11BDAu;
    x0 += ks0; x1 += ks1;
#define TFR(r) { x0 += x1; x1 = rotl32(x1, r); x1 ^= x0; }
    TFR(13) TFR(15) TFR(26) TFR(6)   x0 += ks1; x1 += ks2 + 1u;
    TFR(17) TFR(29) TFR(16) TFR(24)  x0 += ks2; x1 += ks0 + 2u;
    TFR(13) TFR(15) TFR(26) TFR(6)   x0 += ks0; x1 += ks1 + 3u;
    TFR(17) TFR(29) TFR(16) TFR(24)  x0 += ks1; x1 += ks2 + 4u;
    TFR(13) TFR(15) TFR(26) TFR(6)   x0 += ks2; x1 += ks0 + 5u;
#undef TFR
}

__device__ inline float bits_to_unit(unsigned bits) {
    return __uint_as_float((bits >> 9) | 0x3F800000u) - 1.0f;
}

__device__ inline v2f rand_phase(int i) {
    unsigned x0 = 0u, x1 = (unsigned)i;
    threefry2x32(0u, 1u, x0, x1);
    float u = bits_to_unit(x0 ^ x1);
    float ang = 6.283185307179586f * u;
    return (v2f){cosf(ang), sinf(ang)};
}

// ---------------- register twiddles via HW trig (input in REVOLUTIONS) --------
__device__ inline v2f cs_rev(float rev) {
    float r = rev - floorf(rev);
    return (v2f){__builtin_amdgcn_cosf(r), __builtin_amdgcn_sinf(r)};
}

// complex multiply a*b (CONJ: a*conj(b)) — pk_mul + pk_fma with folded fneg
template <bool CONJ>
__device__ inline v2f cmulT(v2f a, v2f b) {
    v2f bb = CONJ ? (v2f){b.x, -b.y} : b;
    v2f ax = __builtin_shufflevector(a, a, 0, 0);
    v2f ay = __builtin_shufflevector(a, a, 1, 1);
    v2f br = __builtin_shufflevector(bb, bb, 1, 0);
    v2f s  = ay * br;
    v2f sn = (v2f){-s.x, s.y};
    return ax * bb + sn;
}

// wave-local lane pull of a v2f (2x ds_bpermute; moves identical bits)
__device__ inline v2f bperm_v2(int lane, v2f v) {
    int rx = __builtin_amdgcn_ds_bpermute(lane << 2, __float_as_int(v.x));
    int ry = __builtin_amdgcn_ds_bpermute(lane << 2, __float_as_int(v.y));
    return (v2f){__int_as_float(rx), __int_as_float(ry)};
}

// ---------------- in-register DFT8 (DIT 2x4) ----------------
template <bool INV>
__device__ inline void dft8(const v2f x[8], v2f y[8]) {
    v2f a0 = x[0] + x[4], a1 = x[0] - x[4];
    v2f a2 = x[2] + x[6], a3 = x[2] - x[6];
    v2f ja3 = INV ? (v2f){-a3.y, a3.x} : (v2f){a3.y, -a3.x};   // ∓i·a3
    v2f E0 = a0 + a2, E2 = a0 - a2;
    v2f E1 = a1 + ja3, E3 = a1 - ja3;
    v2f b0 = x[1] + x[5], b1 = x[1] - x[5];
    v2f b2 = x[3] + x[7], b3 = x[3] - x[7];
    v2f jb3 = INV ? (v2f){-b3.y, b3.x} : (v2f){b3.y, -b3.x};
    v2f O0 = b0 + b2, O2 = b0 - b2;
    v2f O1 = b1 + jb3, O3 = b1 - jb3;
    const float r = 0.70710678118654752f;
    v2f W1 = INV ? (v2f){r * (O1.x - O1.y), r * (O1.x + O1.y)}
                 : (v2f){r * (O1.x + O1.y), r * (O1.y - O1.x)};
    v2f W2 = INV ? (v2f){-O2.y, O2.x} : (v2f){O2.y, -O2.x};
    v2f W3 = INV ? (v2f){-r * (O3.x + O3.y), r * (O3.x - O3.y)}
                 : (v2f){r * (O3.y - O3.x), -r * (O3.x + O3.y)};
    y[0] = E0 + O0;  y[4] = E0 - O0;
    y[1] = E1 + W1;  y[5] = E1 - W1;
    y[2] = E2 + W2;  y[6] = E2 - W2;
    y[3] = E3 + W3;  y[7] = E3 - W3;
}

// ---------------- wave-synchronous 512-pt FFT, radix-8^3 (proven r11) --------
template <bool INV>
__device__ inline void fft512r8(v2f z[8], v2f* __restrict__ L,
                                const v2f tw0[7], const v2f tw1[7], const int lam) {
    v2f y[8], x[8];
    dft8<INV>(z, y);
#pragma unroll
    for (int m = 1; m < 8; ++m) y[m] = cmulT<INV>(y[m], tw0[m - 1]);
#pragma unroll
    for (int m = 0; m < 8; ++m) L[IDX8(8 * lam + m)] = y[m];
#pragma unroll
    for (int m = 0; m < 8; ++m) x[m] = L[IDX8(lam + 64 * m)];
    dft8<INV>(x, y);
#pragma unroll
    for (int m = 1; m < 8; ++m) y[m] = cmulT<INV>(y[m], tw1[m - 1]);
    const int q = lam & 7, p = lam >> 3;
#pragma unroll
    for (int m = 0; m < 8; ++m) L[IDX8(q + 64 * p + 8 * m)] = y[m];
#pragma unroll
    for (int m = 0; m < 8; ++m) x[m] = L[IDX8(lam + 64 * m)];
    dft8<INV>(x, z);
}

// First ISTFT: X=mag*random_phase (each X computed ONCE, Hermitian partner via
// wave-local LDS; all stores precede all reads -> in-order DS pipe, safe)
__global__ __launch_bounds__(256) void k_istft0(const float* __restrict__ mag,
                                                const float* __restrict__ wins,
                                                float* __restrict__ frames) {
    __shared__ v2f L[4][LDSF];
    const int t = threadIdx.x, sub = t >> 6, lam = t & 63;
    const int bt = blockIdx.x * 4 + sub;
    v2f tw0[7], tw1[7];
#pragma unroll
    for (int m = 1; m < 8; ++m) {
        tw0[m - 1] = cs_rev(-(float)(lam * m) * (1.0f / 512.0f));
        tw1[m - 1] = cs_rev(-(float)((lam >> 3) * m) * (1.0f / 64.0f));
    }
    const float* mg = mag + (size_t)bt * NFREQ;
    auto loadX = [&](int k) -> v2f {
        float m = mg[k];
        v2f p = rand_phase(bt * NFREQ + k);
        v2f X = (v2f){m * p.x, m * p.y};
        if (k == 0 || k == 512) X.y = 0.f;   // C2R drops imag of DC/Nyquist
        return X;
    };
    v2f Xr[8];
#pragma unroll
    for (int j = 0; j < 8; ++j) {
        int k = lam + 64 * j;
        Xr[j] = loadX(k);
        L[sub][IDX8(k)] = Xr[j];
    }
    if (lam == 0) L[sub][IDX8(512)] = loadX(512);
    v2f z[8];
#pragma unroll
    for (int j = 0; j < 8; ++j) {
        int k = lam + 64 * j;
        v2f Xk = Xr[j];
        v2f Xc = L[sub][IDX8(512 - k)];     // wave-local, in-order DS pipe
        float ex = 0.5f * (Xk.x + Xc.x), ey = 0.5f * (Xk.y - Xc.y);
        float dx = 0.5f * (Xk.x - Xc.x), dy = 0.5f * (Xk.y + Xc.y);
        v2f c = cs_rev(-(float)k * (1.0f / 1024.0f));   // e^{-i th}
        float ox = c.x * dx + c.y * dy;
        float oy = c.x * dy - c.y * dx;
        z[j] = (v2f){ex - oy, ey + ox};     // Z = Xe + i Xo
    }
    fft512r8<true>(z, &L[sub][0], tw0, tw1, lam);
    v2f* out2 = (v2f*)(frames + (size_t)bt * NFFT);
    const v2f* wn2 = (const v2f*)wins;      // wins pre-scaled by 1/512
#pragma unroll
    for (int j = 0; j < 8; ++j) {
        int n = lam + 64 * j;
        out2[n] = z[j] * wn2[n];
    }
}

// FUSED Griffin-Lim step: STFT(sig) -> normalize -> *mag -> ISTFT -> frames.
// FIX (r12 bug): snapshot z into zo[] BEFORE the unpack/repack loop; bpermute
// reads zo (originals) while z is overwritten — no read-after-write hazard.
__global__ __launch_bounds__(256) void k_fused(const float* __restrict__ sig,
                                               const float* __restrict__ mag,
                                               const float* __restrict__ winf,
                                               const float* __restrict__ wins,
                                               float* __restrict__ frames) {
    __shared__ v2f L[4][LDSF];
    const int t = threadIdx.x, sub = t >> 6, lam = t & 63;
    const int bt = blockIdx.x * 4 + sub;
    const int b = bt / NT, tt = bt - b * NT;
    const v2f* x2 = (const v2f*)(sig + (size_t)b * SIGL + (size_t)tt * HOP);
    const v2f* wf2 = (const v2f*)winf;
    const float* mg = mag + (size_t)bt * NFREQ;
    v2f tw0[7], tw1[7];
#pragma unroll
    for (int m = 1; m < 8; ++m) {
        tw0[m - 1] = cs_rev(-(float)(lam * m) * (1.0f / 512.0f));
        tw1[m - 1] = cs_rev(-(float)((lam >> 3) * m) * (1.0f / 64.0f));
    }
    // forward: window + pack (z[n] = x[2n]w + i x[2n+1]w)
    v2f z[8];
#pragma unroll
    for (int j = 0; j < 8; ++j) {
        int n = lam + 64 * j;
        z[j] = x2[n] * wf2[n];
    }
    fft512r8<false>(z, &L[sub][0], tw0, tw1, lam);
    // snapshot originals (registers), partners via bpermute from zo
    v2f zo[8];
#pragma unroll
    for (int j = 0; j < 8; ++j) zo[j] = z[j];
    const int lp = (64 - lam) & 63;
#pragma unroll
    for (int j = 0; j < 8; ++j) {
        int k = lam + 64 * j;
        v2f Zk = zo[j];
        v2f Zp = bperm_v2(lp, zo[7 - j]);             // lane lp's ORIGINAL slot 7-j
        if (lam == 0) Zp = zo[(8 - j) & 7];           // lane0 pairing j<->(8-j)&7
        v2f c = cs_rev(-(float)k * (1.0f / 1024.0f)); // W^k
        v2f C, D;   // C = X'[k], D = conj(X'[512-k])
        if (lam == 0 && j == 0) {
            float X0 = Zk.x + Zk.y;    // X[0]
            float X5 = Zk.x - Zk.y;    // X[512]
            C = (v2f){X0 * (mg[0]   / fmaxf(1e-10f, fabsf(X0))), 0.f};
            D = (v2f){X5 * (mg[512] / fmaxf(1e-10f, fabsf(X5))), 0.f};
        } else {
            float ex = 0.5f * (Zk.x + Zp.x), ey = 0.5f * (Zk.y - Zp.y);
            float dx = 0.5f * (Zk.x - Zp.x), dy = 0.5f * (Zk.y + Zp.y);
            float ox = dy, oy = -dx;               // O = -i*d
            float Ux = c.x * ox - c.y * oy, Uy = c.x * oy + c.y * ox;
            float X1x = ex + Ux, X1y = ey + Uy;    // X[k]
            float X2x = ex - Ux, X2y = ey - Uy;    // conj(X[512-k])
            float i1 = mg[k]       / fmaxf(1e-10f, sqrtf(X1x * X1x + X1y * X1y));
            float i2 = mg[512 - k] / fmaxf(1e-10f, sqrtf(X2x * X2x + X2y * X2y));
            C = (v2f){X1x * i1, X1y * i1};
            D = (v2f){X2x * i2, X2y * i2};
        }
        // repack with Xk = C, Xc = conj(D)  (verbatim istft pack algebra)
        float ex = 0.5f * (C.x + D.x), ey = 0.5f * (C.y + D.y);
        float dx = 0.5f * (C.x - D.x), dy = 0.5f * (C.y - D.y);
        float ox = c.x * dx + c.y * dy;
        float oy = c.x * dy - c.y * dx;
        z[j] = (v2f){ex - oy, ey + ox};
    }
    fft512r8<true>(z, &L[sub][0], tw0, tw1, lam);
    v2f* out2 = (v2f*)(frames + (size_t)bt * NFFT);
    const v2f* wn2 = (const v2f*)wins;
#pragma unroll
    for (int j = 0; j < 8; ++j) {
        int n = lam + 64 * j;
        out2[n] = z[j] * wn2[n];
    }
}

// overlap-add (gather), float4-vectorized: l 4-aligned => o = l-256t 4-aligned
// => every contribution is a FULL float4 (o in [0,1020]) or fully invalid.
// Ascending-t sum per element == scalar reference order (bit-identical).
__global__ void k_ola(const float* __restrict__ frames, float* __restrict__ sig) {
    int idx4 = blockIdx.x * blockDim.x + threadIdx.x;
    const int SQ = SIGL / 4;               // 64192
    if (idx4 >= NB * SQ) return;
    int b = idx4 / SQ, l = (idx4 - b * SQ) * 4;
    int tlo = (l >= 1021) ? ((l - 765) >> 8) : 0;
    int thi = min(NT - 1, l >> 8);
    float4 s = make_float4(0.f, 0.f, 0.f, 0.f);
    const float* base = frames + (size_t)b * NT * NFFT;
    for (int t = tlo; t <= thi; ++t) {
        const float4 v = *(const float4*)(base + (size_t)t * NFFT + (l - (t << 8)));
        s.x += v.x; s.y += v.y; s.z += v.z; s.w += v.w;
    }
    *(float4*)(sig + (size_t)b * SIGL + l) = s;
}

// ---------------- launcher ----------------
extern "C" void kernel_launch(void* const* d_in, const int* in_sizes, int n_in,
                              void* d_out, int out_size, void* d_ws, size_t ws_size,
                              hipStream_t stream) {
    const float* mel    = (const float*)d_in[0];
    const float* basis  = (const float*)d_in[1];
    const float* smean  = (const float*)d_in[2];
    const float* sscale = (const float*)d_in[3];

    char* ws = (char*)d_ws;
    double* G      = (double*)(ws + OFF_G);
    double* Ginv   = (double*)(ws + OFF_GINV);
    float*  ivT    = (float*) (ws + OFF_INVMEL);
    float*  winf   = (float*) (ws + OFF_WINF);
    float*  wins   = (float*) (ws + OFF_WINS);
    float*  mag    = (float*) (ws + OFF_MAG);
    float*  frames = (float*) (ws + OFF_FR);
    float*  sig    = (float*) (ws + OFF_SIG);
    float*  outp   = (float*)d_out;

    const int olaGrid = (NB * (SIGL / 4) + 255) / 256;

    k_windows<<<1, 256, 0, stream>>>(winf, wins);
    k_gram<<<80, 256, 0, stream>>>(basis, G);
    k_gjinv<<<1, 256, 0, stream>>>(G, Ginv);
    k_invmel<<<(NFREQ * NMEL + 255) / 256, 256, 0, stream>>>(basis, Ginv, ivT);
    k_mag<<<NFRM / MAGROWS, 256, 0, stream>>>(mel, smean, sscale, ivT, mag);

    // iteration 0: random phase fused into first ISTFT
    k_istft0<<<NFRM / 4, 256, 0, stream>>>(mag, wins, frames);
    for (int it = 0; it < NITER; ++it) {
        k_ola<<<olaGrid, 256, 0, stream>>>(frames, sig);
        k_fused<<<NFRM / 4, 256, 0, stream>>>(sig, mag, winf, wins, frames);
    }
    k_ola<<<olaGrid, 256, 0, stream>>>(frames, outp);
}

// Round 14
// 390.180 us; speedup vs baseline: 1.4673x; 1.1025x over previous
//
#include <hip/hip_runtime.h>
#include <math.h>

// ---------------- problem constants ----------------
#define NB     8
#define NT     1000
#define NMEL   80
#define NFREQ  513      // 1024/2+1
#define NFFT   1024
#define WINL   1024
#define HOP    256
#define SIGL   256768   // (NT-1)*HOP + WINL
#define NFRM   8000     // NB*NT
#define NITER  8

// padded LDS indexing: +1 float2 per 8 (breaks stride-8/64 bank patterns)
#define IDX8(x) ((x) + ((x) >> 3))
#define LDSF    584     // IDX8(512)=576 max (istft0 stores X[512]), rounded to 8

// packed 2xf32 — lowers to v_pk_add/mul/fma_f32 on CDNA
typedef float v2f __attribute__((ext_vector_type(2)));

// ---------------- workspace layout (bytes) ----------------
#define OFF_G      ((size_t)0)                       // double G[80][80]
#define SZ_G       ((size_t)NMEL*NMEL*8)
#define OFF_GINV   (OFF_G + SZ_G)
#define SZ_GINV    ((size_t)NMEL*NMEL*8)
#define OFF_INVMEL (OFF_GINV + SZ_GINV)              // float invmelT[80][513]
#define SZ_INVMEL  ((size_t)NFREQ*NMEL*4)
#define OFF_WINF   (OFF_INVMEL + SZ_INVMEL)          // float winf[1024]
#define OFF_WINS   (OFF_WINF + 4096)                 // float wins[1024] (pre-scaled /512)
#define OFF_MAG    (OFF_WINS + 4096)                 // float mag[8000][513]
#define SZ_MAG     ((size_t)NFRM*NFREQ*4)
#define OFF_FR     (OFF_MAG + SZ_MAG)                // float frames[8000][1024]
#define SZ_FR      ((size_t)NFRM*NFFT*4)
#define OFF_SIG    (OFF_FR + SZ_FR)                  // float sig[8][256768]
#define SZ_SIG     ((size_t)NB*SIGL*4)

// ---------------- small precompute kernels ----------------

__global__ void k_windows(float* __restrict__ winf, float* __restrict__ wins) {
    int t = threadIdx.x; // 256 threads
    for (int n = t; n < WINL; n += 256) {
        double w = 0.5 - 0.5 * cos(2.0 * M_PI * (double)n / (double)WINL);
        winf[n] = (float)w;
    }
    __syncthreads();
    {
        float a0 = winf[t], a1 = winf[t + 256], a2 = winf[t + 512], a3 = winf[t + 768];
        float den = a0 * a0;
        den += a1 * a1; den += a2 * a2; den += a3 * a3;
        const float s = 1.0f / 512.0f;  // fold IFFT normalization into synthesis window
        wins[t]       = a0 / den * s;
        wins[t + 256] = a1 / den * s;
        wins[t + 512] = a2 / den * s;
        wins[t + 768] = a3 / den * s;
    }
}

// G = B B^T (f64)
__global__ void k_gram(const float* __restrict__ Bm, double* __restrict__ G) {
    int i = blockIdx.x; // 80 blocks
    for (int j = threadIdx.x; j < NMEL; j += blockDim.x) {
        double s = 0.0;
        for (int f = 0; f < NFREQ; ++f)
            s += (double)Bm[i * NFREQ + f] * (double)Bm[j * NFREQ + f];
        G[i * NMEL + j] = s;
    }
}

// Register-tiled GJ inversion of SPD 80x80 (round-10 version: no spill, I$-resident)
__global__ __launch_bounds__(256, 1) void k_gjinv(const double* __restrict__ G,
                                                  double* __restrict__ Ginv) {
    __shared__ double fcol[2][NMEL];
    __shared__ double prow[2][NMEL];
    double A[5][5];
    const int t = threadIdx.x, tx = t & 15, ty = t >> 4;
    const int R0 = ty * 5, C0 = tx * 5;
#pragma unroll
    for (int r = 0; r < 5; ++r)
#pragma unroll
        for (int c = 0; c < 5; ++c)
            A[r][c] = G[(R0 + r) * NMEL + C0 + c];
    __syncthreads();
    for (int pb = 0; pb < 16; ++pb) {
        const bool rown = (ty == pb), cown = (tx == pb);
#pragma unroll
        for (int pi = 0; pi < 5; ++pi) {
            const int p = pb * 5 + pi;
            const int cur = p & 1;
            if (cown) {
#pragma unroll
                for (int r = 0; r < 5; ++r) fcol[cur][R0 + r] = A[r][pi];
            }
            if (rown) {
#pragma unroll
                for (int c = 0; c < 5; ++c) prow[cur][C0 + c] = A[pi][c];
            }
            __syncthreads();
            const double d = 1.0 / fcol[cur][p];
            double fr[5], pcd[5];
#pragma unroll
            for (int r = 0; r < 5; ++r) fr[r] = fcol[cur][R0 + r];
#pragma unroll
            for (int c = 0; c < 5; ++c) pcd[c] = prow[cur][C0 + c] * d;
#pragma unroll
            for (int r = 0; r < 5; ++r) {
                const bool pr = (r == pi) && rown;
#pragma unroll
                for (int c = 0; c < 5; ++c) {
                    const bool pc = (c == pi) && cown;
                    double nv;
                    if (pr) nv = pc ? d : A[r][c] * d;
                    else    nv = pc ? (-fr[r] * d) : fma(-fr[r], pcd[c], A[r][c]);
                    A[r][c] = nv;
                }
            }
        }
    }
    __syncthreads();
#pragma unroll
    for (int r = 0; r < 5; ++r)
#pragma unroll
        for (int c = 0; c < 5; ++c)
            Ginv[(R0 + r) * NMEL + C0 + c] = A[r][c];
}

// invmelT[m][f] = sum_k B[k][f] * Ginv[k][m]   (TRANSPOSED output)
__global__ void k_invmel(const float* __restrict__ Bm, const double* __restrict__ Ginv,
                         float* __restrict__ ivT) {
    int idx = blockIdx.x * blockDim.x + threadIdx.x;
    if (idx >= NFREQ * NMEL) return;
    int f = idx / NMEL, m = idx - f * NMEL;
    double s = 0.0;
    for (int k = 0; k < NMEL; ++k)
        s += (double)Bm[k * NFREQ + f] * Ginv[k * NMEL + m];
    ivT[m * NFREQ + f] = (float)s;
}

// mag: fused melpow (10^(mel*scale+mean)) + 16 bt-rows per block GEMM-ish
#define MAGROWS 16
__global__ __launch_bounds__(256) void k_mag(const float* __restrict__ mel,
                                             const float* __restrict__ smean,
                                             const float* __restrict__ sscale,
                                             const float* __restrict__ ivT,
                                             float* __restrict__ mag) {
    __shared__ float rows[MAGROWS][NMEL];
    int bt0 = blockIdx.x * MAGROWS;
    for (int e = threadIdx.x; e < MAGROWS * NMEL; e += 256) {
        int m = e % NMEL;
        rows[e / NMEL][m] = exp10f(mel[(size_t)bt0 * NMEL + e] * sscale[m] + smean[m]);
    }
    __syncthreads();
    for (int f = threadIdx.x; f < NFREQ; f += 256) {
        float acc[MAGROWS];
#pragma unroll
        for (int r = 0; r < MAGROWS; ++r) acc[r] = 0.f;
        for (int m = 0; m < NMEL; ++m) {
            float iv = ivT[m * NFREQ + f];
#pragma unroll
            for (int r = 0; r < MAGROWS; ++r) acc[r] = fmaf(rows[r][m], iv, acc[r]);
        }
#pragma unroll
        for (int r = 0; r < MAGROWS; ++r)
            mag[(size_t)(bt0 + r) * NFREQ + f] = fmaxf(1e-10f, acc[r]);
    }
}

// ---------------- threefry2x32 (JAX-exact, partitionable mode) ----------------
__device__ inline unsigned rotl32(unsigned x, int d) { return (x << d) | (x >> (32 - d)); }

__device__ inline void threefry2x32(unsigned k0, unsigned k1, unsigned& x0, unsigned& x1) {
    unsigned ks0 = k0, ks1 = k1, ks2 = k0 ^ k1 ^ 0x1BD11BDAu;
    x0 += ks0; x1 += ks1;
#define TFR(r) { x0 += x1; x1 = rotl32(x1, r); x1 ^= x0; }
    TFR(13) TFR(15) TFR(26) TFR(6)   x0 += ks1; x1 += ks2 + 1u;
    TFR(17) TFR(29) TFR(16) TFR(24)  x0 += ks2; x1 += ks0 + 2u;
    TFR(13) TFR(15) TFR(26) TFR(6)   x0 += ks0; x1 += ks1 + 3u;
    TFR(17) TFR(29) TFR(16) TFR(24)  x0 += ks1; x1 += ks2 + 4u;
    TFR(13) TFR(15) TFR(26) TFR(6)   x0 += ks2; x1 += ks0 + 5u;
#undef TFR
}

__device__ inline float bits_to_unit(unsigned bits) {
    return __uint_as_float((bits >> 9) | 0x3F800000u) - 1.0f;
}

// phase = exp(2*pi*i*u): u in [0,1) IS the angle in revolutions — hw trig direct.
__device__ inline v2f rand_phase(int i) {
    unsigned x0 = 0u, x1 = (unsigned)i;
    threefry2x32(0u, 1u, x0, x1);
    float u = bits_to_unit(x0 ^ x1);
    return (v2f){__builtin_amdgcn_cosf(u), __builtin_amdgcn_sinf(u)};
}

// ---------------- register twiddles via HW trig (input in REVOLUTIONS) --------
__device__ inline v2f cs_rev(float rev) {
    float r = rev - floorf(rev);
    return (v2f){__builtin_amdgcn_cosf(r), __builtin_amdgcn_sinf(r)};
}

// complex multiply a*b (CONJ: a*conj(b)) — pk_mul + pk_fma with folded fneg
template <bool CONJ>
__device__ inline v2f cmulT(v2f a, v2f b) {
    v2f bb = CONJ ? (v2f){b.x, -b.y} : b;
    v2f ax = __builtin_shufflevector(a, a, 0, 0);
    v2f ay = __builtin_shufflevector(a, a, 1, 1);
    v2f br = __builtin_shufflevector(bb, bb, 1, 0);
    v2f s  = ay * br;
    v2f sn = (v2f){-s.x, s.y};
    return ax * bb + sn;
}

// wave-local lane pull of a v2f (2x ds_bpermute; moves identical bits)
__device__ inline v2f bperm_v2(int lane, v2f v) {
    int rx = __builtin_amdgcn_ds_bpermute(lane << 2, __float_as_int(v.x));
    int ry = __builtin_amdgcn_ds_bpermute(lane << 2, __float_as_int(v.y));
    return (v2f){__int_as_float(rx), __int_as_float(ry)};
}

// ---------------- in-register DFT8 (DIT 2x4) ----------------
template <bool INV>
__device__ inline void dft8(const v2f x[8], v2f y[8]) {
    v2f a0 = x[0] + x[4], a1 = x[0] - x[4];
    v2f a2 = x[2] + x[6], a3 = x[2] - x[6];
    v2f ja3 = INV ? (v2f){-a3.y, a3.x} : (v2f){a3.y, -a3.x};   // ∓i·a3
    v2f E0 = a0 + a2, E2 = a0 - a2;
    v2f E1 = a1 + ja3, E3 = a1 - ja3;
    v2f b0 = x[1] + x[5], b1 = x[1] - x[5];
    v2f b2 = x[3] + x[7], b3 = x[3] - x[7];
    v2f jb3 = INV ? (v2f){-b3.y, b3.x} : (v2f){b3.y, -b3.x};
    v2f O0 = b0 + b2, O2 = b0 - b2;
    v2f O1 = b1 + jb3, O3 = b1 - jb3;
    const float r = 0.70710678118654752f;
    v2f W1 = INV ? (v2f){r * (O1.x - O1.y), r * (O1.x + O1.y)}
                 : (v2f){r * (O1.x + O1.y), r * (O1.y - O1.x)};
    v2f W2 = INV ? (v2f){-O2.y, O2.x} : (v2f){O2.y, -O2.x};
    v2f W3 = INV ? (v2f){-r * (O3.x + O3.y), r * (O3.x - O3.y)}
                 : (v2f){r * (O3.y - O3.x), -r * (O3.x + O3.y)};
    y[0] = E0 + O0;  y[4] = E0 - O0;
    y[1] = E1 + W1;  y[5] = E1 - W1;
    y[2] = E2 + W2;  y[6] = E2 - W2;
    y[3] = E3 + W3;  y[7] = E3 - W3;
}

// ---------------- wave-synchronous 512-pt FFT, radix-8^3 (proven r11) --------
template <bool INV>
__device__ inline void fft512r8(v2f z[8], v2f* __restrict__ L,
                                const v2f tw0[7], const v2f tw1[7], const int lam) {
    v2f y[8], x[8];
    dft8<INV>(z, y);
#pragma unroll
    for (int m = 1; m < 8; ++m) y[m] = cmulT<INV>(y[m], tw0[m - 1]);
#pragma unroll
    for (int m = 0; m < 8; ++m) L[IDX8(8 * lam + m)] = y[m];
#pragma unroll
    for (int m = 0; m < 8; ++m) x[m] = L[IDX8(lam + 64 * m)];
    dft8<INV>(x, y);
#pragma unroll
    for (int m = 1; m < 8; ++m) y[m] = cmulT<INV>(y[m], tw1[m - 1]);
    const int q = lam & 7, p = lam >> 3;
#pragma unroll
    for (int m = 0; m < 8; ++m) L[IDX8(q + 64 * p + 8 * m)] = y[m];
#pragma unroll
    for (int m = 0; m < 8; ++m) x[m] = L[IDX8(lam + 64 * m)];
    dft8<INV>(x, z);
}

// First ISTFT: X=mag*random_phase (each X computed ONCE, Hermitian partner via
// wave-local LDS; all stores precede all reads -> in-order DS pipe, safe)
__global__ __launch_bounds__(256) void k_istft0(const float* __restrict__ mag,
                                                const float* __restrict__ wins,
                                                float* __restrict__ frames) {
    __shared__ v2f L[4][LDSF];
    const int t = threadIdx.x, sub = t >> 6, lam = t & 63;
    const int bt = blockIdx.x * 4 + sub;
    v2f tw0[7], tw1[7];
#pragma unroll
    for (int m = 1; m < 8; ++m) {
        tw0[m - 1] = cs_rev(-(float)(lam * m) * (1.0f / 512.0f));
        tw1[m - 1] = cs_rev(-(float)((lam >> 3) * m) * (1.0f / 64.0f));
    }
    const float* mg = mag + (size_t)bt * NFREQ;
    auto loadX = [&](int k) -> v2f {
        float m = mg[k];
        v2f p = rand_phase(bt * NFREQ + k);
        v2f X = (v2f){m * p.x, m * p.y};
        if (k == 0 || k == 512) X.y = 0.f;   // C2R drops imag of DC/Nyquist
        return X;
    };
    v2f Xr[8];
#pragma unroll
    for (int j = 0; j < 8; ++j) {
        int k = lam + 64 * j;
        Xr[j] = loadX(k);
        L[sub][IDX8(k)] = Xr[j];
    }
    if (lam == 0) L[sub][IDX8(512)] = loadX(512);
    v2f z[8];
#pragma unroll
    for (int j = 0; j < 8; ++j) {
        int k = lam + 64 * j;
        v2f Xk = Xr[j];
        v2f Xc = L[sub][IDX8(512 - k)];     // wave-local, in-order DS pipe
        float ex = 0.5f * (Xk.x + Xc.x), ey = 0.5f * (Xk.y - Xc.y);
        float dx = 0.5f * (Xk.x - Xc.x), dy = 0.5f * (Xk.y + Xc.y);
        v2f c = cs_rev(-(float)k * (1.0f / 1024.0f));   // e^{-i th}
        float ox = c.x * dx + c.y * dy;
        float oy = c.x * dy - c.y * dx;
        z[j] = (v2f){ex - oy, ey + ox};     // Z = Xe + i Xo
    }
    fft512r8<true>(z, &L[sub][0], tw0, tw1, lam);
    v2f* out2 = (v2f*)(frames + (size_t)bt * NFFT);
    const v2f* wn2 = (const v2f*)wins;      // wins pre-scaled by 1/512
#pragma unroll
    for (int j = 0; j < 8; ++j) {
        int n = lam + 64 * j;
        out2[n] = z[j] * wn2[n];
    }
}

// FUSED Griffin-Lim step: STFT(sig) -> normalize -> *mag -> ISTFT -> frames.
// r13 zo-snapshot fix retained; normalization via v_rsq (mg * rsqrt(|X|^2)).
__global__ __launch_bounds__(256) void k_fused(const float* __restrict__ sig,
                                               const float* __restrict__ mag,
                                               const float* __restrict__ winf,
                                               const float* __restrict__ wins,
                                               float* __restrict__ frames) {
    __shared__ v2f L[4][LDSF];
    const int t = threadIdx.x, sub = t >> 6, lam = t & 63;
    const int bt = blockIdx.x * 4 + sub;
    const int b = bt / NT, tt = bt - b * NT;
    const v2f* x2 = (const v2f*)(sig + (size_t)b * SIGL + (size_t)tt * HOP);
    const v2f* wf2 = (const v2f*)winf;
    const float* mg = mag + (size_t)bt * NFREQ;
    v2f tw0[7], tw1[7];
#pragma unroll
    for (int m = 1; m < 8; ++m) {
        tw0[m - 1] = cs_rev(-(float)(lam * m) * (1.0f / 512.0f));
        tw1[m - 1] = cs_rev(-(float)((lam >> 3) * m) * (1.0f / 64.0f));
    }
    // forward: window + pack (z[n] = x[2n]w + i x[2n+1]w)
    v2f z[8];
#pragma unroll
    for (int j = 0; j < 8; ++j) {
        int n = lam + 64 * j;
        z[j] = x2[n] * wf2[n];
    }
    fft512r8<false>(z, &L[sub][0], tw0, tw1, lam);
    // snapshot originals (registers), partners via bpermute from zo
    v2f zo[8];
#pragma unroll
    for (int j = 0; j < 8; ++j) zo[j] = z[j];
    const int lp = (64 - lam) & 63;
#pragma unroll
    for (int j = 0; j < 8; ++j) {
        int k = lam + 64 * j;
        v2f Zk = zo[j];
        v2f Zp = bperm_v2(lp, zo[7 - j]);             // lane lp's ORIGINAL slot 7-j
        if (lam == 0) Zp = zo[(8 - j) & 7];           // lane0 pairing j<->(8-j)&7
        v2f c = cs_rev(-(float)k * (1.0f / 1024.0f)); // W^k
        v2f C, D;   // C = X'[k], D = conj(X'[512-k])
        if (lam == 0 && j == 0) {
            float X0 = Zk.x + Zk.y;    // X[0]
            float X5 = Zk.x - Zk.y;    // X[512]
            C = (v2f){X0 * (mg[0]   / fmaxf(1e-10f, fabsf(X0))), 0.f};
            D = (v2f){X5 * (mg[512] / fmaxf(1e-10f, fabsf(X5))), 0.f};
        } else {
            float ex = 0.5f * (Zk.x + Zp.x), ey = 0.5f * (Zk.y - Zp.y);
            float dx = 0.5f * (Zk.x - Zp.x), dy = 0.5f * (Zk.y + Zp.y);
            float ox = dy, oy = -dx;               // O = -i*d
            float Ux = c.x * ox - c.y * oy, Uy = c.x * oy + c.y * ox;
            float X1x = ex + Ux, X1y = ey + Uy;    // X[k]
            float X2x = ex - Ux, X2y = ey - Uy;    // conj(X[512-k])
            float i1 = mg[k]       * rsqrtf(fmaxf(1e-20f, X1x * X1x + X1y * X1y));
            float i2 = mg[512 - k] * rsqrtf(fmaxf(1e-20f, X2x * X2x + X2y * X2y));
            C = (v2f){X1x * i1, X1y * i1};
            D = (v2f){X2x * i2, X2y * i2};
        }
        // repack with Xk = C, Xc = conj(D)  (verbatim istft pack algebra)
        float ex = 0.5f * (C.x + D.x), ey = 0.5f * (C.y + D.y);
        float dx = 0.5f * (C.x - D.x), dy = 0.5f * (C.y - D.y);
        float ox = c.x * dx + c.y * dy;
        float oy = c.x * dy - c.y * dx;
        z[j] = (v2f){ex - oy, ey + ox};
    }
    fft512r8<true>(z, &L[sub][0], tw0, tw1, lam);
    v2f* out2 = (v2f*)(frames + (size_t)bt * NFFT);
    const v2f* wn2 = (const v2f*)wins;
#pragma unroll
    for (int j = 0; j < 8; ++j) {
        int n = lam + 64 * j;
        out2[n] = z[j] * wn2[n];
    }
}

// overlap-add (gather), float4-vectorized: l 4-aligned => o = l-256t 4-aligned
// => every contribution is a FULL float4 (o in [0,1020]) or fully invalid.
// Ascending-t sum per element == scalar reference order (bit-identical).
__global__ void k_ola(const float* __restrict__ frames, float* __restrict__ sig) {
    int idx4 = blockIdx.x * blockDim.x + threadIdx.x;
    const int SQ = SIGL / 4;               // 64192
    if (idx4 >= NB * SQ) return;
    int b = idx4 / SQ, l = (idx4 - b * SQ) * 4;
    int tlo = (l >= 1021) ? ((l - 765) >> 8) : 0;
    int thi = min(NT - 1, l >> 8);
    float4 s = make_float4(0.f, 0.f, 0.f, 0.f);
    const float* base = frames + (size_t)b * NT * NFFT;
    for (int t = tlo; t <= thi; ++t) {
        const float4 v = *(const float4*)(base + (size_t)t * NFFT + (l - (t << 8)));
        s.x += v.x; s.y += v.y; s.z += v.z; s.w += v.w;
    }
    *(float4*)(sig + (size_t)b * SIGL + l) = s;
}

// ---------------- launcher ----------------
extern "C" void kernel_launch(void* const* d_in, const int* in_sizes, int n_in,
                              void* d_out, int out_size, void* d_ws, size_t ws_size,
                              hipStream_t stream) {
    const float* mel    = (const float*)d_in[0];
    const float* basis  = (const float*)d_in[1];
    const float* smean  = (const float*)d_in[2];
    const float* sscale = (const float*)d_in[3];

    char* ws = (char*)d_ws;
    double* G      = (double*)(ws + OFF_G);
    double* Ginv   = (double*)(ws + OFF_GINV);
    float*  ivT    = (float*) (ws + OFF_INVMEL);
    float*  winf   = (float*) (ws + OFF_WINF);
    float*  wins   = (float*) (ws + OFF_WINS);
    float*  mag    = (float*) (ws + OFF_MAG);
    float*  frames = (float*) (ws + OFF_FR);
    float*  sig    = (float*) (ws + OFF_SIG);
    float*  outp   = (float*)d_out;

    const int olaGrid = (NB * (SIGL / 4) + 255) / 256;

    k_windows<<<1, 256, 0, stream>>>(winf, wins);
    k_gram<<<80, 256, 0, stream>>>(basis, G);
    k_gjinv<<<1, 256, 0, stream>>>(G, Ginv);
    k_invmel<<<(NFREQ * NMEL + 255) / 256, 256, 0, stream>>>(basis, Ginv, ivT);
    k_mag<<<NFRM / MAGROWS, 256, 0, stream>>>(mel, smean, sscale, ivT, mag);

    // iteration 0: random phase fused into first ISTFT
    k_istft0<<<NFRM / 4, 256, 0, stream>>>(mag, wins, frames);
    for (int it = 0; it < NITER; ++it) {
        k_ola<<<olaGrid, 256, 0, stream>>>(frames, sig);
        k_fused<<<NFRM / 4, 256, 0, stream>>>(sig, mag, winf, wins, frames);
    }
    k_ola<<<olaGrid, 256, 0, stream>>>(frames, outp);
}